// Round 14
// baseline (132.719 us; speedup 1.0000x reference)
//
#include <hip/hip_runtime.h>
#include <hip/hip_bf16.h>
#include <math.h>

#define EPS_BN 1e-5f

constexpr int BATCH = 32;
constexpr int NPTS  = 2048;
constexpr int BP    = BATCH * NPTS;   // 65536

using s16x8 = __attribute__((ext_vector_type(8))) short;
using u16x4 = __attribute__((ext_vector_type(4))) unsigned short;
using u32x4 = __attribute__((ext_vector_type(4))) unsigned;
using f32x4 = __attribute__((ext_vector_type(4))) float;

static __device__ __forceinline__ unsigned short f2bf(float f) {
  union { float f; unsigned u; } x{f};
  unsigned r = x.u + 0x7fffu + ((x.u >> 16) & 1u);  // RNE
  return (unsigned short)(r >> 16);
}
static __device__ __forceinline__ float bf2f(unsigned short s) {
  union { unsigned u; float f; } x;
  x.u = ((unsigned)s) << 16;
  return x.f;
}
static __device__ __forceinline__ unsigned pk2bf(float lo, float hi) {
  __hip_bfloat162 t = __float22bfloat162_rn(float2{lo, hi});
  unsigned r;
  __builtin_memcpy(&r, &t, 4);
  return r;
}

static __device__ __forceinline__ void gload_lds16(const void* g, void* l) {
  __builtin_amdgcn_global_load_lds((const __attribute__((address_space(1))) void*)g,
                                   (__attribute__((address_space(3))) void*)l, 16, 0, 0);
}

static __device__ __forceinline__ float wave_reduce_add(float v) {
#pragma unroll
  for (int off = 32; off > 0; off >>= 1) v += __shfl_xor(v, off);
  return v;
}

// keep-6-smallest, ASCENDING list, depth-1 branchless insert (1 min + 5 med3).
static __device__ __forceinline__ void ins6(float (&nn)[6], float c) {
  float b0 = fminf(nn[0], c);
  float b1 = __builtin_amdgcn_fmed3f(c, nn[1], nn[0]);
  float b2 = __builtin_amdgcn_fmed3f(c, nn[2], nn[1]);
  float b3 = __builtin_amdgcn_fmed3f(c, nn[3], nn[2]);
  float b4 = __builtin_amdgcn_fmed3f(c, nn[4], nn[3]);
  float b5 = __builtin_amdgcn_fmed3f(c, nn[5], nn[4]);
  nn[0] = b0; nn[1] = b1; nn[2] = b2; nn[3] = b3; nn[4] = b4; nn[5] = b5;
}

// ---------------- curvature + fused layer1 (+ weight-conversion plane y==32) ----------------
// rank by r = 0.5|q|^2 - p.q  (d2 = |p|^2 + 2r); 8-deep register prefetch hides LDS latency.
constexpr int CHP = 257;  // float4 stride per 256-pt chunk
__global__ __launch_bounds__(256) void curv1_kernel(const float* __restrict__ x,
                                                    const float* __restrict__ c1w,
                                                    const float* __restrict__ c1b,
                                                    const float* __restrict__ w3,
                                                    const float* __restrict__ w2,
                                                    unsigned short* __restrict__ w3bf,
                                                    unsigned short* __restrict__ w2bf,
                                                    unsigned short* __restrict__ z1bf,
                                                    float* __restrict__ part) {
  if (blockIdx.y == 32) {  // weight-conversion plane: 64 blocks, no barriers
    int g = blockIdx.x * 256 + threadIdx.x;  // 0..16383
    {
      const float4 v0 = ((const float4*)w3)[g];
      const float4 v1 = ((const float4*)w3)[g + 16384];
      u16x4 a{f2bf(v0.x), f2bf(v0.y), f2bf(v0.z), f2bf(v0.w)};
      u16x4 b{f2bf(v1.x), f2bf(v1.y), f2bf(v1.z), f2bf(v1.w)};
      *(u16x4*)(w3bf + (size_t)g * 4) = a;
      *(u16x4*)(w3bf + (size_t)(g + 16384) * 4) = b;
    }
    if (g < 2048) {
      const float4 v = ((const float4*)w2)[g];
      u16x4 a{f2bf(v.x), f2bf(v.y), f2bf(v.z), f2bf(v.w)};
      *(u16x4*)(w2bf + (size_t)g * 4) = a;
    }
    return;
  }
  __shared__ float4 pts[8 * CHP];   // 32896 B
  __shared__ float wT[4 * 64], lb1[64], sfeat[32 * 4];
  __shared__ float ls[256], lq[256];
  int b = blockIdx.y;
  const float* xb = x + (size_t)b * NPTS * 3;
  int tid = threadIdx.x;
  {
    int k = tid >> 6, c = tid & 63;
    wT[k * 64 + c] = c1w[c * 4 + k];
    if (tid < 64) lb1[tid] = c1b[tid];
  }
#pragma unroll
  for (int k = 0; k < 8; k++) {
    int i = k * 256 + tid;
    float qx = xb[i * 3 + 0], qy = xb[i * 3 + 1], qz = xb[i * 3 + 2];
    pts[k * CHP + tid] = make_float4(qx, qy, qz, 0.5f * (qx * qx + qy * qy + qz * qz));
  }
  __syncthreads();
  int row = blockIdx.x * 32 + (tid >> 3);
  int sub = tid & 7;
  float4 p = pts[(row >> 8) * CHP + (row & 255)];
  float px = p.x, py = p.y, pz = p.z;
  float nn[6];
#pragma unroll
  for (int j = 0; j < 6; j++) nn[j] = 3.4e38f;
  const float4* cp = pts + sub * CHP;
  // 8-deep double-buffered register prefetch: loads for batch k+1 in flight
  // while batch k's 8 insert chains issue (~144 cyc) -- covers ~120 cyc LDS latency.
  float4 buf[8];
#pragma unroll
  for (int t = 0; t < 8; t++) buf[t] = cp[t];
  for (int j = 8; j < 256; j += 8) {
    float4 nxt[8];
#pragma unroll
    for (int t = 0; t < 8; t++) nxt[t] = cp[j + t];
#pragma unroll
    for (int t = 0; t < 8; t++)
      ins6(nn, fmaf(-px, buf[t].x, fmaf(-py, buf[t].y, fmaf(-pz, buf[t].z, buf[t].w))));
#pragma unroll
    for (int t = 0; t < 8; t++) buf[t] = nxt[t];
  }
#pragma unroll
  for (int t = 0; t < 8; t++)
    ins6(nn, fmaf(-px, buf[t].x, fmaf(-py, buf[t].y, fmaf(-pz, buf[t].z, buf[t].w))));
  // butterfly merge across the 8 subthreads: snapshot partner's list, then insert.
#pragma unroll
  for (int m = 1; m <= 4; m <<= 1) {
    float other[6];
#pragma unroll
    for (int k = 0; k < 6; k++) other[k] = __shfl_xor(nn[k], m);
#pragma unroll
    for (int k = 0; k < 6; k++) ins6(nn, other[k]);
  }
  if (sub == 0) {
    float p2 = px * px + py * py + pz * pz;
    float dm = 0.f;
#pragma unroll
    for (int i = 1; i < 6; i++) dm += sqrtf(fmaxf(fmaf(2.f, nn[i], p2), 0.f));
    dm *= 0.2f;
    float curv = 1.0f / (1e-8f + dm);
    int lr = tid >> 3;
    sfeat[lr * 4 + 0] = px;
    sfeat[lr * 4 + 1] = py;
    sfeat[lr * 4 + 2] = pz;
    sfeat[lr * 4 + 3] = curv;
  }
  __syncthreads();
  // fused layer1: 32 rows x 64 cols; thread = (col, rowgroup of 8)
  {
    int c = tid & 63, rg = tid >> 6;
    float w0 = wT[c], w1 = wT[64 + c], w2v = wT[128 + c], w3v = wT[192 + c];
    float bb = lb1[c];
    int growbase = b * NPTS + blockIdx.x * 32;
    float s = 0.f, q = 0.f;
#pragma unroll
    for (int i = 0; i < 8; i++) {
      int lr = rg * 8 + i;
      float4 f = *(const float4*)(sfeat + lr * 4);
      float acc = bb + f.x * w0 + f.y * w1 + f.z * w2v + f.w * w3v;
      s += acc;
      q += acc * acc;
      z1bf[(size_t)(growbase + lr) * 64 + c] = f2bf(acc);
    }
    ls[tid] = s;
    lq[tid] = q;
  }
  __syncthreads();
  if (tid < 64) {
    float ss = 0.f, qq = 0.f;
#pragma unroll
    for (int i = 0; i < 4; i++) { ss += ls[i * 64 + tid]; qq += lq[i * 64 + tid]; }
    size_t bid = (size_t)b * 64 + blockIdx.x;
    part[(bid * 64 + tid) * 2 + 0] = ss;
    part[(bid * 64 + tid) * 2 + 1] = qq;
  }
}

// ---------------- generic BN finalize from P partials ----------------
template <int C, int P>
__global__ __launch_bounds__(256) void bnfinP_kernel(const float* __restrict__ part,
                                                     const float* __restrict__ g,
                                                     const float* __restrict__ be,
                                                     float* __restrict__ scale,
                                                     float* __restrict__ shift) {
  int c = blockIdx.x, tid = threadIdx.x;
  float s = 0.f, q = 0.f;
  for (int i = tid; i < P; i += 256) {
    s += part[((size_t)i * C + c) * 2 + 0];
    q += part[((size_t)i * C + c) * 2 + 1];
  }
  __shared__ float ls[256], lq[256];
  ls[tid] = s; lq[tid] = q;
  __syncthreads();
  for (int off = 128; off > 0; off >>= 1) {
    if (tid < off) { ls[tid] += ls[tid + off]; lq[tid] += lq[tid + off]; }
    __syncthreads();
  }
  if (tid == 0) {
    float m = ls[0] * (1.0f / 65536.0f);
    float v = lq[0] * (1.0f / 65536.0f) - m * m;
    float a = g[c] / sqrtf(v + EPS_BN);
    scale[c] = a;
    shift[c] = be[c] - m * a;
  }
}

// ---------------- layer2 MFMA: relu(bn1(z1bf)) @ W2^T + b2 -> z2bf + BN2 stats ----------------
__global__ __launch_bounds__(256) void gemm2_mfma_kernel(const unsigned short* __restrict__ z1bf,
                                                         const float* __restrict__ s1,
                                                         const float* __restrict__ h1,
                                                         const unsigned short* __restrict__ w2bf,
                                                         const float* __restrict__ bias2,
                                                         unsigned short* __restrict__ z2bf,
                                                         float* __restrict__ part2) {
  __shared__ char lds[33280];  // A @0 (16KB), B @16384 (16KB), s1h1 @32768
  float* ls1 = (float*)(lds + 32768);
  float* lh1 = ls1 + 64;
  int tid = threadIdx.x;
  int row0 = blockIdx.x * 128;
  if (tid < 64) { ls1[tid] = s1[tid]; lh1[tid] = h1[tid]; }

  s16x8 araw[4], braw[4];
#pragma unroll
  for (int i = 0; i < 4; i++) {
    int L = tid + 256 * i;
    araw[i] = *(const s16x8*)(z1bf + (size_t)row0 * 64 + (size_t)L * 8);
    braw[i] = *(const s16x8*)(w2bf + (size_t)L * 8);
  }
  __syncthreads();

#pragma unroll
  for (int i = 0; i < 4; i++) {
    int L = tid + 256 * i;
    int row = L >> 3, grp = L & 7, k0 = grp * 8;
    float4 sA = *(const float4*)(ls1 + k0);
    float4 sB = *(const float4*)(ls1 + k0 + 4);
    float4 hA = *(const float4*)(lh1 + k0);
    float4 hB = *(const float4*)(lh1 + k0 + 4);
    float v0 = fmaxf(bf2f((unsigned short)araw[i][0]) * sA.x + hA.x, 0.f);
    float v1 = fmaxf(bf2f((unsigned short)araw[i][1]) * sA.y + hA.y, 0.f);
    float v2 = fmaxf(bf2f((unsigned short)araw[i][2]) * sA.z + hA.z, 0.f);
    float v3 = fmaxf(bf2f((unsigned short)araw[i][3]) * sA.w + hA.w, 0.f);
    float v4 = fmaxf(bf2f((unsigned short)araw[i][4]) * sB.x + hB.x, 0.f);
    float v5 = fmaxf(bf2f((unsigned short)araw[i][5]) * sB.y + hB.y, 0.f);
    float v6 = fmaxf(bf2f((unsigned short)araw[i][6]) * sB.z + hB.z, 0.f);
    float v7 = fmaxf(bf2f((unsigned short)araw[i][7]) * sB.w + hB.w, 0.f);
    u32x4 pa = {pk2bf(v0, v1), pk2bf(v2, v3), pk2bf(v4, v5), pk2bf(v6, v7)};
    *(u32x4*)(lds + row * 128 + ((grp ^ (row & 7)) << 4)) = pa;
    *(s16x8*)(lds + 16384 + row * 128 + ((grp ^ (row & 7)) << 4)) = braw[i];
  }
  __syncthreads();

  int w = tid >> 6, lane = tid & 63;
  int wm = w >> 1, wn = w & 1;
  int lrow = lane & 15, lg = lane >> 4;
  int sw = (lrow & 7) << 4;
  f32x4 acc[4][4] = {};
#pragma unroll
  for (int kstep = 0; kstep < 2; kstep++) {
    s16x8 a[4], bfr[4];
#pragma unroll
    for (int m = 0; m < 4; m++) {
      int row = wm * 64 + m * 16 + lrow;
      int byte = row * 128 + ((kstep * 64 + lg * 16) ^ sw);
      a[m] = *(const s16x8*)(lds + byte);
    }
#pragma unroll
    for (int n = 0; n < 4; n++) {
      int col = wn * 64 + n * 16 + lrow;
      int byte = 16384 + col * 128 + ((kstep * 64 + lg * 16) ^ sw);
      bfr[n] = *(const s16x8*)(lds + byte);
    }
#pragma unroll
    for (int m = 0; m < 4; m++)
#pragma unroll
      for (int n = 0; n < 4; n++)
        acc[m][n] = __builtin_amdgcn_mfma_f32_16x16x32_bf16(a[m], bfr[n], acc[m][n], 0, 0, 0);
  }
  __syncthreads();

  float* sS = (float*)lds;
  float* sQ = sS + 256;
#pragma unroll
  for (int n = 0; n < 4; n++) {
    int col = wn * 64 + n * 16 + lrow;
    float bb = bias2[col];
    float s = 0.f, q = 0.f;
#pragma unroll
    for (int m = 0; m < 4; m++) {
#pragma unroll
      for (int r = 0; r < 4; r++) {
        float v = acc[m][n][r] + bb;
        s += v;
        q += v * v;
        int row = row0 + wm * 64 + m * 16 + lg * 4 + r;
        z2bf[(size_t)row * 128 + col] = f2bf(v);
      }
    }
    s += __shfl_xor(s, 16); s += __shfl_xor(s, 32);
    q += __shfl_xor(q, 16); q += __shfl_xor(q, 32);
    if (lane < 16) {
      int cidx = wn * 64 + n * 16 + lane;
      sS[wm * 128 + cidx] = s;
      sQ[wm * 128 + cidx] = q;
    }
  }
  __syncthreads();
  if (tid < 128) {
    part2[((size_t)blockIdx.x * 128 + tid) * 2 + 0] = sS[tid] + sS[128 + tid];
    part2[((size_t)blockIdx.x * 128 + tid) * 2 + 1] = sQ[tid] + sQ[128 + tid];
  }
}

// ---------------- layer3 MFMA: one block per 128-row panel, loop over 8 col-blocks ----------------
__global__ __launch_bounds__(256) void gemm3_mfma_kernel(const unsigned short* __restrict__ z2bf,
                                                         const float* __restrict__ s2,
                                                         const float* __restrict__ h2,
                                                         const unsigned short* __restrict__ wbf,
                                                         const float* __restrict__ bias3,
                                                         float* __restrict__ pS,
                                                         float* __restrict__ pQ,
                                                         float* __restrict__ pMx,
                                                         float* __restrict__ pMn) {
  __shared__ char lds[70656];  // A[0,32768) B[32768,65536) scratch[65536,69632) s2h2[69632,70656)
  float* ls2 = (float*)(lds + 69632);
  float* lh2 = ls2 + 128;
  int tid = threadIdx.x;
  int w = tid >> 6, lane = tid & 63;
  int bid = blockIdx.x;                 // 512 blocks, XCD-chunked
  int rblk = (bid & 7) * 64 + (bid >> 3);
  int row0 = rblk * 128;

  if (tid < 128) { ls2[tid] = s2[tid]; lh2[tid] = h2[tid]; }
  s16x8 araw[8];
#pragma unroll
  for (int i = 0; i < 8; i++) {
    int L = tid + 256 * i;
    int row = L >> 4, gc = L & 15;
    araw[i] = *(const s16x8*)(z2bf + (size_t)(row0 + row) * 128 + gc * 8);
  }
  __syncthreads();
#pragma unroll
  for (int i = 0; i < 8; i++) {
    int L = tid + 256 * i;
    int row = L >> 4, gc = L & 15, k0 = gc * 8;
    float4 sA = *(const float4*)(ls2 + k0);
    float4 sB = *(const float4*)(ls2 + k0 + 4);
    float4 hA = *(const float4*)(lh2 + k0);
    float4 hB = *(const float4*)(lh2 + k0 + 4);
    float v0 = fmaxf(bf2f((unsigned short)araw[i][0]) * sA.x + hA.x, 0.f);
    float v1 = fmaxf(bf2f((unsigned short)araw[i][1]) * sA.y + hA.y, 0.f);
    float v2 = fmaxf(bf2f((unsigned short)araw[i][2]) * sA.z + hA.z, 0.f);
    float v3 = fmaxf(bf2f((unsigned short)araw[i][3]) * sA.w + hA.w, 0.f);
    float v4 = fmaxf(bf2f((unsigned short)araw[i][4]) * sB.x + hB.x, 0.f);
    float v5 = fmaxf(bf2f((unsigned short)araw[i][5]) * sB.y + hB.y, 0.f);
    float v6 = fmaxf(bf2f((unsigned short)araw[i][6]) * sB.z + hB.z, 0.f);
    float v7 = fmaxf(bf2f((unsigned short)araw[i][7]) * sB.w + hB.w, 0.f);
    u32x4 pa = {pk2bf(v0, v1), pk2bf(v2, v3), pk2bf(v4, v5), pk2bf(v6, v7)};
    *(u32x4*)(lds + row * 256 + ((gc ^ (row & 7)) << 4)) = pa;
  }

  int wm = w >> 1, wn = w & 1;
  int lrow = lane & 15, lg = lane >> 4;
  int sw = (lrow & 7) << 4;
  float* sS = (float*)(lds + 65536);   // [2][128]
  float* sQ = sS + 256;
  float* sMx = sQ + 256;
  float* sMn = sMx + 256;

  for (int cblk = 0; cblk < 8; cblk++) {
    int col0 = cblk * 128;
#pragma unroll
    for (int i = 0; i < 8; i++) {
      int ldsoff = w * 8192 + i * 1024;
      int lin = ldsoff + lane * 16;
      int row = lin >> 8;
      int gc = (lin >> 4) & 15;
      int gcl = gc ^ (row & 7);
      gload_lds16(wbf + (size_t)(col0 + row) * 128 + gcl * 8, &lds[32768 + ldsoff]);
    }
    __syncthreads();

    f32x4 acc[4][4] = {};
#pragma unroll
    for (int kstep = 0; kstep < 4; kstep++) {
      s16x8 a[4], b[4];
#pragma unroll
      for (int m = 0; m < 4; m++) {
        int row = wm * 64 + m * 16 + lrow;
        int byte = row * 256 + ((kstep * 64 + lg * 16) ^ sw);
        a[m] = *(const s16x8*)(lds + byte);
      }
#pragma unroll
      for (int n = 0; n < 4; n++) {
        int col = wn * 64 + n * 16 + lrow;
        int byte = 32768 + col * 256 + ((kstep * 64 + lg * 16) ^ sw);
        b[n] = *(const s16x8*)(lds + byte);
      }
#pragma unroll
      for (int m = 0; m < 4; m++)
#pragma unroll
        for (int n = 0; n < 4; n++)
          acc[m][n] = __builtin_amdgcn_mfma_f32_16x16x32_bf16(a[m], b[n], acc[m][n], 0, 0, 0);
    }

    // RAW per-column stats; sum/sumsq in the loop, max/min via max3/min3 trees
#pragma unroll
    for (int n = 0; n < 4; n++) {
      float v[16];
      float s = 0.f, q = 0.f;
#pragma unroll
      for (int m = 0; m < 4; m++)
#pragma unroll
        for (int r = 0; r < 4; r++) {
          float t = acc[m][n][r];
          v[m * 4 + r] = t;
          s += t;
          q = fmaf(t, t, q);
        }
      float mx = fmaxf(fmaxf(fmaxf(fmaxf(v[0], v[1]), v[2]),
                             fmaxf(fmaxf(v[3], v[4]), v[5])),
                       fmaxf(fmaxf(fmaxf(v[6], v[7]), v[8]),
                             fmaxf(fmaxf(v[9], v[10]), v[11])));
      mx = fmaxf(mx, fmaxf(fmaxf(v[12], v[13]), fmaxf(v[14], v[15])));
      float mn = fminf(fminf(fminf(fminf(v[0], v[1]), v[2]),
                             fminf(fminf(v[3], v[4]), v[5])),
                       fminf(fminf(fminf(v[6], v[7]), v[8]),
                             fminf(fminf(v[9], v[10]), v[11])));
      mn = fminf(mn, fminf(fminf(v[12], v[13]), fminf(v[14], v[15])));
      s += __shfl_xor(s, 16); s += __shfl_xor(s, 32);
      q += __shfl_xor(q, 16); q += __shfl_xor(q, 32);
      mx = fmaxf(mx, __shfl_xor(mx, 16)); mx = fmaxf(mx, __shfl_xor(mx, 32));
      mn = fminf(mn, __shfl_xor(mn, 16)); mn = fminf(mn, __shfl_xor(mn, 32));
      if (lane < 16) {
        int cidx = wn * 64 + n * 16 + lane;
        sS[wm * 128 + cidx] = s;
        sQ[wm * 128 + cidx] = q;
        sMx[wm * 128 + cidx] = mx;
        sMn[wm * 128 + cidx] = mn;
      }
    }
    __syncthreads();
    if (tid < 128) {
      float bcol = bias3[col0 + tid];
      float S = sS[tid] + sS[128 + tid];
      float Q = sQ[tid] + sQ[128 + tid];
      size_t o = (size_t)rblk * 1024 + col0 + tid;
      pS[o] = S + 128.f * bcol;
      pQ[o] = Q + 2.f * bcol * S + 128.f * bcol * bcol;
      pMx[o] = fmaxf(sMx[tid], sMx[128 + tid]) + bcol;
      pMn[o] = fminf(sMn[tid], sMn[128 + tid]) + bcol;
    }
    __syncthreads();
  }
}

// ---------------- bn3 finalize + masked max-pool ----------------
__global__ __launch_bounds__(256) void bn3fin_pool_kernel(const float* __restrict__ pS,
                                                          const float* __restrict__ pQ,
                                                          const float* __restrict__ pMx,
                                                          const float* __restrict__ pMn,
                                                          const float* __restrict__ g,
                                                          const float* __restrict__ be,
                                                          float* __restrict__ pooled) {
  int tid = threadIdx.x;
  int chl = tid & 15, grp = tid >> 4;
  int c = blockIdx.x * 16 + chl;
  float s = 0.f, q = 0.f;
  for (int i = grp; i < 512; i += 16) {
    s += pS[(size_t)i * 1024 + c];
    q += pQ[(size_t)i * 1024 + c];
  }
  __shared__ float ls[256], lq[256], sa[16], sc[16];
  ls[chl * 16 + grp] = s;
  lq[chl * 16 + grp] = q;
  __syncthreads();
  if (tid < 16) {
    float ss = 0.f, qq = 0.f;
#pragma unroll
    for (int i = 0; i < 16; i++) { ss += ls[tid * 16 + i]; qq += lq[tid * 16 + i]; }
    float m = ss * (1.0f / 65536.0f);
    float v = qq * (1.0f / 65536.0f) - m * m;
    float a = g[blockIdx.x * 16 + tid] / sqrtf(v + EPS_BN);
    sa[tid] = a;
    sc[tid] = be[blockIdx.x * 16 + tid] - m * a;
  }
  __syncthreads();
  for (int idx = tid; idx < 512; idx += 256) {
    int b = idx >> 4, l = idx & 15;
    int cc = blockIdx.x * 16 + l;
    float mx = -3.4e38f, mn = 3.4e38f;
    for (int i = 0; i < 16; i++) {
      mx = fmaxf(mx, pMx[(size_t)(b * 16 + i) * 1024 + cc]);
      mn = fminf(mn, pMn[(size_t)(b * 16 + i) * 1024 + cc]);
    }
    float a = sa[l];
    float v = (a > 0.f) ? (a * mx + sc[l]) : (a * mn + sc[l]);
    pooled[(size_t)b * 1024 + cc] = fmaxf(v, 0.f);
  }
}

// ---------------- fc1: wave-per-output ----------------
__global__ __launch_bounds__(256) void fc1_kernel(const float* __restrict__ pooled,
                                                  const float* __restrict__ w,
                                                  const float* __restrict__ bias,
                                                  float* __restrict__ zf1) {
  int gw = blockIdx.x * 4 + (threadIdx.x >> 6);
  int lane = threadIdx.x & 63;
  int b = gw >> 9, o = gw & 511;
  const float4* pr = (const float4*)(pooled + (size_t)b * 1024);
  const float4* wr = (const float4*)(w + (size_t)o * 1024);
  float acc = 0.f;
#pragma unroll
  for (int i = 0; i < 4; i++) {
    int k = lane + i * 64;
    float4 p = pr[k], q = wr[k];
    acc += p.x * q.x + p.y * q.y + p.z * q.z + p.w * q.w;
  }
  acc = wave_reduce_add(acc);
  if (lane == 0) zf1[gw] = acc + bias[o];
}

__global__ __launch_bounds__(256) void statsF_kernel(const float* __restrict__ z,
                                                     const float* __restrict__ g,
                                                     const float* __restrict__ be, int C,
                                                     float* __restrict__ scale,
                                                     float* __restrict__ shift) {
  int c = blockIdx.x * 256 + threadIdx.x;
  if (c >= C) return;
  float s = 0.f, q = 0.f;
  for (int b = 0; b < 32; b++) {
    float v = z[(size_t)b * C + c];
    s += v;
    q += v * v;
  }
  float m = s * (1.0f / 32.0f);
  float v = q * (1.0f / 32.0f) - m * m;
  float a = g[c] / sqrtf(v + EPS_BN);
  scale[c] = a;
  shift[c] = be[c] - m * a;
}

// ---------------- fc2: wave-per-output ----------------
__global__ __launch_bounds__(256) void fc2_kernel(const float* __restrict__ zf1,
                                                  const float* __restrict__ sf1,
                                                  const float* __restrict__ hf1,
                                                  const float* __restrict__ w,
                                                  const float* __restrict__ bias,
                                                  float* __restrict__ zf2) {
  int gw = blockIdx.x * 4 + (threadIdx.x >> 6);
  int lane = threadIdx.x & 63;
  int b = gw >> 8, o = gw & 255;
  const float4* zr = (const float4*)(zf1 + (size_t)b * 512);
  const float4* sr = (const float4*)sf1;
  const float4* hr = (const float4*)hf1;
  const float4* wr = (const float4*)(w + (size_t)o * 512);
  float acc = 0.f;
#pragma unroll
  for (int i = 0; i < 2; i++) {
    int k = lane + i * 64;
    float4 z = zr[k], s = sr[k], h = hr[k], q = wr[k];
    float v0 = fmaxf(z.x * s.x + h.x, 0.f);
    float v1 = fmaxf(z.y * s.y + h.y, 0.f);
    float v2 = fmaxf(z.z * s.z + h.z, 0.f);
    float v3 = fmaxf(z.w * s.w + h.w, 0.f);
    acc += v0 * q.x + v1 * q.y + v2 * q.z + v3 * q.w;
  }
  acc = wave_reduce_add(acc);
  if (lane == 0) zf2[gw] = acc + bias[o];
}

// ---------------- head: per-block BN-f2 stats + 4 waves x 10 dots + log_softmax ----------------
__global__ __launch_bounds__(256) void head_kernel(const float* __restrict__ zf2,
                                                   const float* __restrict__ gf2,
                                                   const float* __restrict__ bef2,
                                                   const float* __restrict__ w,
                                                   const float* __restrict__ bias,
                                                   float* __restrict__ out) {
  int b = blockIdx.x, tid = threadIdx.x;
  int wv = tid >> 6, lane = tid & 63;
  __shared__ float ssf[256], shf[256], lg[40], red[2];
  {
    float s = 0.f, q = 0.f;
    for (int bb = 0; bb < 32; bb++) {
      float v = zf2[(size_t)bb * 256 + tid];
      s += v;
      q += v * v;
    }
    float m = s * (1.0f / 32.0f);
    float var = q * (1.0f / 32.0f) - m * m;
    float a = gf2[tid] / sqrtf(var + EPS_BN);
    ssf[tid] = a;
    shf[tid] = bef2[tid] - m * a;
  }
  __syncthreads();
  float4 z = ((const float4*)(zf2 + (size_t)b * 256))[lane];
  float4 s = ((const float4*)ssf)[lane];
  float4 h = ((const float4*)shf)[lane];
  float v0 = fmaxf(z.x * s.x + h.x, 0.f);
  float v1 = fmaxf(z.y * s.y + h.y, 0.f);
  float v2 = fmaxf(z.z * s.z + h.z, 0.f);
  float v3 = fmaxf(z.w * s.w + h.w, 0.f);
  for (int r = 0; r < 10; r++) {
    int o = wv * 10 + r;
    float4 q = ((const float4*)(w + (size_t)o * 256))[lane];
    float a = v0 * q.x + v1 * q.y + v2 * q.z + v3 * q.w;
    a = wave_reduce_add(a);
    if (lane == 0) lg[o] = a + bias[o];
  }
  __syncthreads();
  if (tid == 0) {
    float mx = -3.4e38f;
    for (int i = 0; i < 40; i++) mx = fmaxf(mx, lg[i]);
    float sum = 0.f;
    for (int i = 0; i < 40; i++) sum += expf(lg[i] - mx);
    red[0] = mx;
    red[1] = logf(sum);
  }
  __syncthreads();
  if (tid < 40) out[(size_t)b * 40 + tid] = lg[tid] - red[0] - red[1];
}

extern "C" void kernel_launch(void* const* d_in, const int* in_sizes, int n_in,
                              void* d_out, int out_size, void* d_ws, size_t ws_size,
                              hipStream_t stream) {
  const float* x    = (const float*)d_in[0];
  const float* c1w  = (const float*)d_in[1];
  const float* c1b  = (const float*)d_in[2];
  const float* g1   = (const float*)d_in[3];
  const float* be1  = (const float*)d_in[4];
  const float* c2w  = (const float*)d_in[5];
  const float* c2b  = (const float*)d_in[6];
  const float* g2   = (const float*)d_in[7];
  const float* be2  = (const float*)d_in[8];
  const float* c3w  = (const float*)d_in[9];
  const float* c3b  = (const float*)d_in[10];
  const float* g3   = (const float*)d_in[11];
  const float* be3  = (const float*)d_in[12];
  const float* f1w  = (const float*)d_in[13];
  const float* f1b  = (const float*)d_in[14];
  const float* gf1  = (const float*)d_in[15];
  const float* bef1 = (const float*)d_in[16];
  const float* f2w  = (const float*)d_in[17];
  const float* f2b  = (const float*)d_in[18];
  const float* gf2  = (const float*)d_in[19];
  const float* bef2 = (const float*)d_in[20];
  const float* ow   = (const float*)d_in[21];
  const float* ob   = (const float*)d_in[22];
  float* out = (float*)d_out;

  float* W = (float*)d_ws;
  float* pS     = W;                   // 524288
  float* pQ     = pS + 524288;
  float* pMx    = pQ + 524288;
  float* pMn    = pMx + 524288;
  float* part   = pMn + 524288;        // 262144 (BN1 partials 2048x64x2)
  float* part2  = part + 262144;       // 131072 (BN2 partials 512x128x2)
  float* pooled = part2 + 131072;      // 32768
  float* zf1    = pooled + 32768;      // 16384
  float* zf2    = zf1 + 16384;         // 8192
  float* s1     = zf2 + 8192;          // 64
  float* h1     = s1 + 64;
  float* s2     = h1 + 64;             // 128
  float* h2     = s2 + 128;
  float* sf1    = h2 + 128;            // 512
  float* hf1    = sf1 + 512;
  unsigned short* wbf  = (unsigned short*)(hf1 + 512);   // 131072 shorts (w3 bf16)
  unsigned short* w2bf = wbf + 131072;                   // 8192 shorts (w2 bf16)
  unsigned short* z1bf = w2bf + 8192;                    // 65536*64
  unsigned short* z2bf = z1bf + (size_t)BP * 64;         // 65536*128

  curv1_kernel<<<dim3(64, 33), 256, 0, stream>>>(x, c1w, c1b, c3w, c2w, wbf, w2bf, z1bf, part);
  bnfinP_kernel<64, 2048><<<64, 256, 0, stream>>>(part, g1, be1, s1, h1);
  gemm2_mfma_kernel<<<512, 256, 0, stream>>>(z1bf, s1, h1, w2bf, c2b, z2bf, part2);
  bnfinP_kernel<128, 512><<<128, 256, 0, stream>>>(part2, g2, be2, s2, h2);
  gemm3_mfma_kernel<<<512, 256, 0, stream>>>(z2bf, s2, h2, wbf, c3b, pS, pQ, pMx, pMn);
  bn3fin_pool_kernel<<<64, 256, 0, stream>>>(pS, pQ, pMx, pMn, g3, be3, pooled);
  fc1_kernel<<<4096, 256, 0, stream>>>(pooled, f1w, f1b, zf1);
  statsF_kernel<<<2, 256, 0, stream>>>(zf1, gf1, bef1, 512, sf1, hf1);
  fc2_kernel<<<2048, 256, 0, stream>>>(zf1, sf1, hf1, f2w, f2b, zf2);
  head_kernel<<<32, 256, 0, stream>>>(zf2, gf2, bef2, ow, ob, out);
}

// Round 15
// 126.161 us; speedup vs baseline: 1.0520x; 1.0520x over previous
//
#include <hip/hip_runtime.h>
#include <hip/hip_bf16.h>
#include <math.h>

#define EPS_BN 1e-5f

constexpr int BATCH = 32;
constexpr int NPTS  = 2048;
constexpr int BP    = BATCH * NPTS;   // 65536

using s16x8 = __attribute__((ext_vector_type(8))) short;
using u16x4 = __attribute__((ext_vector_type(4))) unsigned short;
using u32x4 = __attribute__((ext_vector_type(4))) unsigned;
using f32x4 = __attribute__((ext_vector_type(4))) float;

static __device__ __forceinline__ unsigned short f2bf(float f) {
  union { float f; unsigned u; } x{f};
  unsigned r = x.u + 0x7fffu + ((x.u >> 16) & 1u);  // RNE
  return (unsigned short)(r >> 16);
}
static __device__ __forceinline__ float bf2f(unsigned short s) {
  union { unsigned u; float f; } x;
  x.u = ((unsigned)s) << 16;
  return x.f;
}
static __device__ __forceinline__ unsigned pk2bf(float lo, float hi) {
  __hip_bfloat162 t = __float22bfloat162_rn(float2{lo, hi});
  unsigned r;
  __builtin_memcpy(&r, &t, 4);
  return r;
}

static __device__ __forceinline__ void gload_lds16(const void* g, void* l) {
  __builtin_amdgcn_global_load_lds((const __attribute__((address_space(1))) void*)g,
                                   (__attribute__((address_space(3))) void*)l, 16, 0, 0);
}

static __device__ __forceinline__ float wave_reduce_add(float v) {
#pragma unroll
  for (int off = 32; off > 0; off >>= 1) v += __shfl_xor(v, off);
  return v;
}

// keep-6-smallest, ASCENDING list, depth-1 branchless insert (1 min + 5 med3).
static __device__ __forceinline__ void ins6(float (&nn)[6], float c) {
  float b0 = fminf(nn[0], c);
  float b1 = __builtin_amdgcn_fmed3f(c, nn[1], nn[0]);
  float b2 = __builtin_amdgcn_fmed3f(c, nn[2], nn[1]);
  float b3 = __builtin_amdgcn_fmed3f(c, nn[3], nn[2]);
  float b4 = __builtin_amdgcn_fmed3f(c, nn[4], nn[3]);
  float b5 = __builtin_amdgcn_fmed3f(c, nn[5], nn[4]);
  nn[0] = b0; nn[1] = b1; nn[2] = b2; nn[3] = b3; nn[4] = b4; nn[5] = b5;
}

// ---------------- curvature + fused layer1 (+ weight-conversion plane y==32) ----------------
// rank by r = 0.5|q|^2 - p.q. Each thread scans its 256-pt chunk ONCE and maintains
// TWO rows' top-6 lists: halves LDS reads, two independent med3 chains hide latency.
constexpr int CHP = 257;  // float4 stride per 256-pt chunk
__global__ __launch_bounds__(256) void curv1_kernel(const float* __restrict__ x,
                                                    const float* __restrict__ c1w,
                                                    const float* __restrict__ c1b,
                                                    const float* __restrict__ w3,
                                                    const float* __restrict__ w2,
                                                    unsigned short* __restrict__ w3bf,
                                                    unsigned short* __restrict__ w2bf,
                                                    unsigned short* __restrict__ z1bf,
                                                    float* __restrict__ part) {
  int tid = threadIdx.x;
  if (blockIdx.y == 32) {  // weight-conversion plane: 32 blocks, no barriers
    int g = blockIdx.x * 256 + tid;  // 0..8191
#pragma unroll
    for (int t = 0; t < 4; t++) {
      int gg = g + t * 8192;
      const float4 v = ((const float4*)w3)[gg];
      u16x4 a{f2bf(v.x), f2bf(v.y), f2bf(v.z), f2bf(v.w)};
      *(u16x4*)(w3bf + (size_t)gg * 4) = a;
    }
    if (g < 2048) {
      const float4 v = ((const float4*)w2)[g];
      u16x4 a{f2bf(v.x), f2bf(v.y), f2bf(v.z), f2bf(v.w)};
      *(u16x4*)(w2bf + (size_t)g * 4) = a;
    }
    return;
  }
  __shared__ float4 pts[8 * CHP];   // 32896 B
  __shared__ float wT[4 * 64], lb1[64], sfeat[64 * 4];
  __shared__ float ls[256], lq[256];
  int b = blockIdx.y;
  const float* xb = x + (size_t)b * NPTS * 3;
  {
    int k = tid >> 6, c = tid & 63;
    wT[k * 64 + c] = c1w[c * 4 + k];
    if (tid < 64) lb1[tid] = c1b[tid];
  }
#pragma unroll
  for (int k = 0; k < 8; k++) {
    int i = k * 256 + tid;
    float qx = xb[i * 3 + 0], qy = xb[i * 3 + 1], qz = xb[i * 3 + 2];
    pts[k * CHP + tid] = make_float4(qx, qy, qz, 0.5f * (qx * qx + qy * qy + qz * qz));
  }
  __syncthreads();
  int pr = tid >> 3;   // row-pair index 0..31
  int sub = tid & 7;   // chunk index
  int rA = blockIdx.x * 64 + pr * 2;
  int rB = rA + 1;
  float4 pA = pts[(rA >> 8) * CHP + (rA & 255)];
  float4 pB = pts[(rB >> 8) * CHP + (rB & 255)];
  float nnA[6], nnB[6];
#pragma unroll
  for (int j = 0; j < 6; j++) { nnA[j] = 3.4e38f; nnB[j] = 3.4e38f; }
  const float4* cp = pts + sub * CHP;
  for (int j = 0; j < 256; j += 4) {
    float4 q0 = cp[j + 0], q1 = cp[j + 1], q2 = cp[j + 2], q3 = cp[j + 3];
    ins6(nnA, fmaf(-pA.x, q0.x, fmaf(-pA.y, q0.y, fmaf(-pA.z, q0.z, q0.w))));
    ins6(nnB, fmaf(-pB.x, q0.x, fmaf(-pB.y, q0.y, fmaf(-pB.z, q0.z, q0.w))));
    ins6(nnA, fmaf(-pA.x, q1.x, fmaf(-pA.y, q1.y, fmaf(-pA.z, q1.z, q1.w))));
    ins6(nnB, fmaf(-pB.x, q1.x, fmaf(-pB.y, q1.y, fmaf(-pB.z, q1.z, q1.w))));
    ins6(nnA, fmaf(-pA.x, q2.x, fmaf(-pA.y, q2.y, fmaf(-pA.z, q2.z, q2.w))));
    ins6(nnB, fmaf(-pB.x, q2.x, fmaf(-pB.y, q2.y, fmaf(-pB.z, q2.z, q2.w))));
    ins6(nnA, fmaf(-pA.x, q3.x, fmaf(-pA.y, q3.y, fmaf(-pA.z, q3.z, q3.w))));
    ins6(nnB, fmaf(-pB.x, q3.x, fmaf(-pB.y, q3.y, fmaf(-pB.z, q3.z, q3.w))));
  }
  // butterfly merge across the 8 subthreads: snapshot partner lists, then insert.
#pragma unroll
  for (int m = 1; m <= 4; m <<= 1) {
    float oA[6], oB[6];
#pragma unroll
    for (int k = 0; k < 6; k++) { oA[k] = __shfl_xor(nnA[k], m); oB[k] = __shfl_xor(nnB[k], m); }
#pragma unroll
    for (int k = 0; k < 6; k++) { ins6(nnA, oA[k]); ins6(nnB, oB[k]); }
  }
  if (sub == 0) {
    float p2A = pA.x * pA.x + pA.y * pA.y + pA.z * pA.z;
    float p2B = pB.x * pB.x + pB.y * pB.y + pB.z * pB.z;
    float dmA = 0.f, dmB = 0.f;
#pragma unroll
    for (int i = 1; i < 6; i++) {
      dmA += sqrtf(fmaxf(fmaf(2.f, nnA[i], p2A), 0.f));
      dmB += sqrtf(fmaxf(fmaf(2.f, nnB[i], p2B), 0.f));
    }
    int lrA = pr * 2;
    sfeat[lrA * 4 + 0] = pA.x;
    sfeat[lrA * 4 + 1] = pA.y;
    sfeat[lrA * 4 + 2] = pA.z;
    sfeat[lrA * 4 + 3] = 1.0f / (1e-8f + 0.2f * dmA);
    sfeat[lrA * 4 + 4] = pB.x;
    sfeat[lrA * 4 + 5] = pB.y;
    sfeat[lrA * 4 + 6] = pB.z;
    sfeat[lrA * 4 + 7] = 1.0f / (1e-8f + 0.2f * dmB);
  }
  __syncthreads();
  // fused layer1: 64 rows x 64 cols; thread = (col, rowgroup of 16)
  {
    int c = tid & 63, rg = tid >> 6;
    float w0 = wT[c], w1 = wT[64 + c], w2v = wT[128 + c], w3v = wT[192 + c];
    float bb = lb1[c];
    int growbase = b * NPTS + blockIdx.x * 64;
    float s = 0.f, q = 0.f;
#pragma unroll
    for (int i = 0; i < 16; i++) {
      int lr = rg * 16 + i;
      float4 f = *(const float4*)(sfeat + lr * 4);
      float acc = bb + f.x * w0 + f.y * w1 + f.z * w2v + f.w * w3v;
      s += acc;
      q += acc * acc;
      z1bf[(size_t)(growbase + lr) * 64 + c] = f2bf(acc);
    }
    ls[tid] = s;
    lq[tid] = q;
  }
  __syncthreads();
  if (tid < 64) {
    float ss = 0.f, qq = 0.f;
#pragma unroll
    for (int i = 0; i < 4; i++) { ss += ls[i * 64 + tid]; qq += lq[i * 64 + tid]; }
    size_t bid = (size_t)b * 32 + blockIdx.x;
    part[(bid * 64 + tid) * 2 + 0] = ss;
    part[(bid * 64 + tid) * 2 + 1] = qq;
  }
}

// ---------------- generic BN finalize from P partials ----------------
template <int C, int P>
__global__ __launch_bounds__(256) void bnfinP_kernel(const float* __restrict__ part,
                                                     const float* __restrict__ g,
                                                     const float* __restrict__ be,
                                                     float* __restrict__ scale,
                                                     float* __restrict__ shift) {
  int c = blockIdx.x, tid = threadIdx.x;
  float s = 0.f, q = 0.f;
  for (int i = tid; i < P; i += 256) {
    s += part[((size_t)i * C + c) * 2 + 0];
    q += part[((size_t)i * C + c) * 2 + 1];
  }
  __shared__ float ls[256], lq[256];
  ls[tid] = s; lq[tid] = q;
  __syncthreads();
  for (int off = 128; off > 0; off >>= 1) {
    if (tid < off) { ls[tid] += ls[tid + off]; lq[tid] += lq[tid + off]; }
    __syncthreads();
  }
  if (tid == 0) {
    float m = ls[0] * (1.0f / 65536.0f);
    float v = lq[0] * (1.0f / 65536.0f) - m * m;
    float a = g[c] / sqrtf(v + EPS_BN);
    scale[c] = a;
    shift[c] = be[c] - m * a;
  }
}

// ---------------- layer2 MFMA: relu(bn1(z1bf)) @ W2^T + b2 -> z2bf + BN2 stats ----------------
__global__ __launch_bounds__(256) void gemm2_mfma_kernel(const unsigned short* __restrict__ z1bf,
                                                         const float* __restrict__ s1,
                                                         const float* __restrict__ h1,
                                                         const unsigned short* __restrict__ w2bf,
                                                         const float* __restrict__ bias2,
                                                         unsigned short* __restrict__ z2bf,
                                                         float* __restrict__ part2) {
  __shared__ char lds[33280];  // A @0 (16KB), B @16384 (16KB), s1h1 @32768
  float* ls1 = (float*)(lds + 32768);
  float* lh1 = ls1 + 64;
  int tid = threadIdx.x;
  int row0 = blockIdx.x * 128;
  if (tid < 64) { ls1[tid] = s1[tid]; lh1[tid] = h1[tid]; }

  s16x8 araw[4], braw[4];
#pragma unroll
  for (int i = 0; i < 4; i++) {
    int L = tid + 256 * i;
    araw[i] = *(const s16x8*)(z1bf + (size_t)row0 * 64 + (size_t)L * 8);
    braw[i] = *(const s16x8*)(w2bf + (size_t)L * 8);
  }
  __syncthreads();

#pragma unroll
  for (int i = 0; i < 4; i++) {
    int L = tid + 256 * i;
    int row = L >> 3, grp = L & 7, k0 = grp * 8;
    float4 sA = *(const float4*)(ls1 + k0);
    float4 sB = *(const float4*)(ls1 + k0 + 4);
    float4 hA = *(const float4*)(lh1 + k0);
    float4 hB = *(const float4*)(lh1 + k0 + 4);
    float v0 = fmaxf(bf2f((unsigned short)araw[i][0]) * sA.x + hA.x, 0.f);
    float v1 = fmaxf(bf2f((unsigned short)araw[i][1]) * sA.y + hA.y, 0.f);
    float v2 = fmaxf(bf2f((unsigned short)araw[i][2]) * sA.z + hA.z, 0.f);
    float v3 = fmaxf(bf2f((unsigned short)araw[i][3]) * sA.w + hA.w, 0.f);
    float v4 = fmaxf(bf2f((unsigned short)araw[i][4]) * sB.x + hB.x, 0.f);
    float v5 = fmaxf(bf2f((unsigned short)araw[i][5]) * sB.y + hB.y, 0.f);
    float v6 = fmaxf(bf2f((unsigned short)araw[i][6]) * sB.z + hB.z, 0.f);
    float v7 = fmaxf(bf2f((unsigned short)araw[i][7]) * sB.w + hB.w, 0.f);
    u32x4 pa = {pk2bf(v0, v1), pk2bf(v2, v3), pk2bf(v4, v5), pk2bf(v6, v7)};
    *(u32x4*)(lds + row * 128 + ((grp ^ (row & 7)) << 4)) = pa;
    *(s16x8*)(lds + 16384 + row * 128 + ((grp ^ (row & 7)) << 4)) = braw[i];
  }
  __syncthreads();

  int w = tid >> 6, lane = tid & 63;
  int wm = w >> 1, wn = w & 1;
  int lrow = lane & 15, lg = lane >> 4;
  int sw = (lrow & 7) << 4;
  f32x4 acc[4][4] = {};
#pragma unroll
  for (int kstep = 0; kstep < 2; kstep++) {
    s16x8 a[4], bfr[4];
#pragma unroll
    for (int m = 0; m < 4; m++) {
      int row = wm * 64 + m * 16 + lrow;
      int byte = row * 128 + ((kstep * 64 + lg * 16) ^ sw);
      a[m] = *(const s16x8*)(lds + byte);
    }
#pragma unroll
    for (int n = 0; n < 4; n++) {
      int col = wn * 64 + n * 16 + lrow;
      int byte = 16384 + col * 128 + ((kstep * 64 + lg * 16) ^ sw);
      bfr[n] = *(const s16x8*)(lds + byte);
    }
#pragma unroll
    for (int m = 0; m < 4; m++)
#pragma unroll
      for (int n = 0; n < 4; n++)
        acc[m][n] = __builtin_amdgcn_mfma_f32_16x16x32_bf16(a[m], bfr[n], acc[m][n], 0, 0, 0);
  }
  __syncthreads();

  float* sS = (float*)lds;
  float* sQ = sS + 256;
#pragma unroll
  for (int n = 0; n < 4; n++) {
    int col = wn * 64 + n * 16 + lrow;
    float bb = bias2[col];
    float s = 0.f, q = 0.f;
#pragma unroll
    for (int m = 0; m < 4; m++) {
#pragma unroll
      for (int r = 0; r < 4; r++) {
        float v = acc[m][n][r] + bb;
        s += v;
        q += v * v;
        int row = row0 + wm * 64 + m * 16 + lg * 4 + r;
        z2bf[(size_t)row * 128 + col] = f2bf(v);
      }
    }
    s += __shfl_xor(s, 16); s += __shfl_xor(s, 32);
    q += __shfl_xor(q, 16); q += __shfl_xor(q, 32);
    if (lane < 16) {
      int cidx = wn * 64 + n * 16 + lane;
      sS[wm * 128 + cidx] = s;
      sQ[wm * 128 + cidx] = q;
    }
  }
  __syncthreads();
  if (tid < 128) {
    part2[((size_t)blockIdx.x * 128 + tid) * 2 + 0] = sS[tid] + sS[128 + tid];
    part2[((size_t)blockIdx.x * 128 + tid) * 2 + 1] = sQ[tid] + sQ[128 + tid];
  }
}

// ---------------- layer3 MFMA: one block per 128-row panel, loop over 8 col-blocks ----------------
__global__ __launch_bounds__(256) void gemm3_mfma_kernel(const unsigned short* __restrict__ z2bf,
                                                         const float* __restrict__ s2,
                                                         const float* __restrict__ h2,
                                                         const unsigned short* __restrict__ wbf,
                                                         const float* __restrict__ bias3,
                                                         float* __restrict__ pS,
                                                         float* __restrict__ pQ,
                                                         float* __restrict__ pMx,
                                                         float* __restrict__ pMn) {
  __shared__ char lds[70656];  // A[0,32768) B[32768,65536) scratch[65536,69632) s2h2[69632,70656)
  float* ls2 = (float*)(lds + 69632);
  float* lh2 = ls2 + 128;
  int tid = threadIdx.x;
  int w = tid >> 6, lane = tid & 63;
  int bid = blockIdx.x;                 // 512 blocks, XCD-chunked
  int rblk = (bid & 7) * 64 + (bid >> 3);
  int row0 = rblk * 128;

  if (tid < 128) { ls2[tid] = s2[tid]; lh2[tid] = h2[tid]; }
  s16x8 araw[8];
#pragma unroll
  for (int i = 0; i < 8; i++) {
    int L = tid + 256 * i;
    int row = L >> 4, gc = L & 15;
    araw[i] = *(const s16x8*)(z2bf + (size_t)(row0 + row) * 128 + gc * 8);
  }
  __syncthreads();
#pragma unroll
  for (int i = 0; i < 8; i++) {
    int L = tid + 256 * i;
    int row = L >> 4, gc = L & 15, k0 = gc * 8;
    float4 sA = *(const float4*)(ls2 + k0);
    float4 sB = *(const float4*)(ls2 + k0 + 4);
    float4 hA = *(const float4*)(lh2 + k0);
    float4 hB = *(const float4*)(lh2 + k0 + 4);
    float v0 = fmaxf(bf2f((unsigned short)araw[i][0]) * sA.x + hA.x, 0.f);
    float v1 = fmaxf(bf2f((unsigned short)araw[i][1]) * sA.y + hA.y, 0.f);
    float v2 = fmaxf(bf2f((unsigned short)araw[i][2]) * sA.z + hA.z, 0.f);
    float v3 = fmaxf(bf2f((unsigned short)araw[i][3]) * sA.w + hA.w, 0.f);
    float v4 = fmaxf(bf2f((unsigned short)araw[i][4]) * sB.x + hB.x, 0.f);
    float v5 = fmaxf(bf2f((unsigned short)araw[i][5]) * sB.y + hB.y, 0.f);
    float v6 = fmaxf(bf2f((unsigned short)araw[i][6]) * sB.z + hB.z, 0.f);
    float v7 = fmaxf(bf2f((unsigned short)araw[i][7]) * sB.w + hB.w, 0.f);
    u32x4 pa = {pk2bf(v0, v1), pk2bf(v2, v3), pk2bf(v4, v5), pk2bf(v6, v7)};
    *(u32x4*)(lds + row * 256 + ((gc ^ (row & 7)) << 4)) = pa;
  }

  int wm = w >> 1, wn = w & 1;
  int lrow = lane & 15, lg = lane >> 4;
  int sw = (lrow & 7) << 4;
  float* sS = (float*)(lds + 65536);   // [2][128]
  float* sQ = sS + 256;
  float* sMx = sQ + 256;
  float* sMn = sMx + 256;

  for (int cblk = 0; cblk < 8; cblk++) {
    int col0 = cblk * 128;
#pragma unroll
    for (int i = 0; i < 8; i++) {
      int ldsoff = w * 8192 + i * 1024;
      int lin = ldsoff + lane * 16;
      int row = lin >> 8;
      int gc = (lin >> 4) & 15;
      int gcl = gc ^ (row & 7);
      gload_lds16(wbf + (size_t)(col0 + row) * 128 + gcl * 8, &lds[32768 + ldsoff]);
    }
    __syncthreads();

    f32x4 acc[4][4] = {};
#pragma unroll
    for (int kstep = 0; kstep < 4; kstep++) {
      s16x8 a[4], b[4];
#pragma unroll
      for (int m = 0; m < 4; m++) {
        int row = wm * 64 + m * 16 + lrow;
        int byte = row * 256 + ((kstep * 64 + lg * 16) ^ sw);
        a[m] = *(const s16x8*)(lds + byte);
      }
#pragma unroll
      for (int n = 0; n < 4; n++) {
        int col = wn * 64 + n * 16 + lrow;
        int byte = 32768 + col * 256 + ((kstep * 64 + lg * 16) ^ sw);
        b[n] = *(const s16x8*)(lds + byte);
      }
#pragma unroll
      for (int m = 0; m < 4; m++)
#pragma unroll
        for (int n = 0; n < 4; n++)
          acc[m][n] = __builtin_amdgcn_mfma_f32_16x16x32_bf16(a[m], b[n], acc[m][n], 0, 0, 0);
    }

    // RAW per-column stats; sum/sumsq in the loop, max/min via max3/min3 trees
#pragma unroll
    for (int n = 0; n < 4; n++) {
      float v[16];
      float s = 0.f, q = 0.f;
#pragma unroll
      for (int m = 0; m < 4; m++)
#pragma unroll
        for (int r = 0; r < 4; r++) {
          float t = acc[m][n][r];
          v[m * 4 + r] = t;
          s += t;
          q = fmaf(t, t, q);
        }
      float mx = fmaxf(fmaxf(fmaxf(fmaxf(v[0], v[1]), v[2]),
                             fmaxf(fmaxf(v[3], v[4]), v[5])),
                       fmaxf(fmaxf(fmaxf(v[6], v[7]), v[8]),
                             fmaxf(fmaxf(v[9], v[10]), v[11])));
      mx = fmaxf(mx, fmaxf(fmaxf(v[12], v[13]), fmaxf(v[14], v[15])));
      float mn = fminf(fminf(fminf(fminf(v[0], v[1]), v[2]),
                             fminf(fminf(v[3], v[4]), v[5])),
                       fminf(fminf(fminf(v[6], v[7]), v[8]),
                             fminf(fminf(v[9], v[10]), v[11])));
      mn = fminf(mn, fminf(fminf(v[12], v[13]), fminf(v[14], v[15])));
      s += __shfl_xor(s, 16); s += __shfl_xor(s, 32);
      q += __shfl_xor(q, 16); q += __shfl_xor(q, 32);
      mx = fmaxf(mx, __shfl_xor(mx, 16)); mx = fmaxf(mx, __shfl_xor(mx, 32));
      mn = fminf(mn, __shfl_xor(mn, 16)); mn = fminf(mn, __shfl_xor(mn, 32));
      if (lane < 16) {
        int cidx = wn * 64 + n * 16 + lane;
        sS[wm * 128 + cidx] = s;
        sQ[wm * 128 + cidx] = q;
        sMx[wm * 128 + cidx] = mx;
        sMn[wm * 128 + cidx] = mn;
      }
    }
    __syncthreads();
    if (tid < 128) {
      float bcol = bias3[col0 + tid];
      float S = sS[tid] + sS[128 + tid];
      float Q = sQ[tid] + sQ[128 + tid];
      size_t o = (size_t)rblk * 1024 + col0 + tid;
      pS[o] = S + 128.f * bcol;
      pQ[o] = Q + 2.f * bcol * S + 128.f * bcol * bcol;
      pMx[o] = fmaxf(sMx[tid], sMx[128 + tid]) + bcol;
      pMn[o] = fminf(sMn[tid], sMn[128 + tid]) + bcol;
    }
    __syncthreads();
  }
}

// ---------------- bn3 finalize + masked max-pool ----------------
__global__ __launch_bounds__(256) void bn3fin_pool_kernel(const float* __restrict__ pS,
                                                          const float* __restrict__ pQ,
                                                          const float* __restrict__ pMx,
                                                          const float* __restrict__ pMn,
                                                          const float* __restrict__ g,
                                                          const float* __restrict__ be,
                                                          float* __restrict__ pooled) {
  int tid = threadIdx.x;
  int chl = tid & 15, grp = tid >> 4;
  int c = blockIdx.x * 16 + chl;
  float s = 0.f, q = 0.f;
  for (int i = grp; i < 512; i += 16) {
    s += pS[(size_t)i * 1024 + c];
    q += pQ[(size_t)i * 1024 + c];
  }
  __shared__ float ls[256], lq[256], sa[16], sc[16];
  ls[chl * 16 + grp] = s;
  lq[chl * 16 + grp] = q;
  __syncthreads();
  if (tid < 16) {
    float ss = 0.f, qq = 0.f;
#pragma unroll
    for (int i = 0; i < 16; i++) { ss += ls[tid * 16 + i]; qq += lq[tid * 16 + i]; }
    float m = ss * (1.0f / 65536.0f);
    float v = qq * (1.0f / 65536.0f) - m * m;
    float a = g[blockIdx.x * 16 + tid] / sqrtf(v + EPS_BN);
    sa[tid] = a;
    sc[tid] = be[blockIdx.x * 16 + tid] - m * a;
  }
  __syncthreads();
  for (int idx = tid; idx < 512; idx += 256) {
    int b = idx >> 4, l = idx & 15;
    int cc = blockIdx.x * 16 + l;
    float mx = -3.4e38f, mn = 3.4e38f;
    for (int i = 0; i < 16; i++) {
      mx = fmaxf(mx, pMx[(size_t)(b * 16 + i) * 1024 + cc]);
      mn = fminf(mn, pMn[(size_t)(b * 16 + i) * 1024 + cc]);
    }
    float a = sa[l];
    float v = (a > 0.f) ? (a * mx + sc[l]) : (a * mn + sc[l]);
    pooled[(size_t)b * 1024 + cc] = fmaxf(v, 0.f);
  }
}

// ---------------- fc1: wave-per-output ----------------
__global__ __launch_bounds__(256) void fc1_kernel(const float* __restrict__ pooled,
                                                  const float* __restrict__ w,
                                                  const float* __restrict__ bias,
                                                  float* __restrict__ zf1) {
  int gw = blockIdx.x * 4 + (threadIdx.x >> 6);
  int lane = threadIdx.x & 63;
  int b = gw >> 9, o = gw & 511;
  const float4* pr = (const float4*)(pooled + (size_t)b * 1024);
  const float4* wr = (const float4*)(w + (size_t)o * 1024);
  float acc = 0.f;
#pragma unroll
  for (int i = 0; i < 4; i++) {
    int k = lane + i * 64;
    float4 p = pr[k], q = wr[k];
    acc += p.x * q.x + p.y * q.y + p.z * q.z + p.w * q.w;
  }
  acc = wave_reduce_add(acc);
  if (lane == 0) zf1[gw] = acc + bias[o];
}

__global__ __launch_bounds__(256) void statsF_kernel(const float* __restrict__ z,
                                                     const float* __restrict__ g,
                                                     const float* __restrict__ be, int C,
                                                     float* __restrict__ scale,
                                                     float* __restrict__ shift) {
  int c = blockIdx.x * 256 + threadIdx.x;
  if (c >= C) return;
  float s = 0.f, q = 0.f;
  for (int b = 0; b < 32; b++) {
    float v = z[(size_t)b * C + c];
    s += v;
    q += v * v;
  }
  float m = s * (1.0f / 32.0f);
  float v = q * (1.0f / 32.0f) - m * m;
  float a = g[c] / sqrtf(v + EPS_BN);
  scale[c] = a;
  shift[c] = be[c] - m * a;
}

// ---------------- fc2: wave-per-output ----------------
__global__ __launch_bounds__(256) void fc2_kernel(const float* __restrict__ zf1,
                                                  const float* __restrict__ sf1,
                                                  const float* __restrict__ hf1,
                                                  const float* __restrict__ w,
                                                  const float* __restrict__ bias,
                                                  float* __restrict__ zf2) {
  int gw = blockIdx.x * 4 + (threadIdx.x >> 6);
  int lane = threadIdx.x & 63;
  int b = gw >> 8, o = gw & 255;
  const float4* zr = (const float4*)(zf1 + (size_t)b * 512);
  const float4* sr = (const float4*)sf1;
  const float4* hr = (const float4*)hf1;
  const float4* wr = (const float4*)(w + (size_t)o * 512);
  float acc = 0.f;
#pragma unroll
  for (int i = 0; i < 2; i++) {
    int k = lane + i * 64;
    float4 z = zr[k], s = sr[k], h = hr[k], q = wr[k];
    float v0 = fmaxf(z.x * s.x + h.x, 0.f);
    float v1 = fmaxf(z.y * s.y + h.y, 0.f);
    float v2 = fmaxf(z.z * s.z + h.z, 0.f);
    float v3 = fmaxf(z.w * s.w + h.w, 0.f);
    acc += v0 * q.x + v1 * q.y + v2 * q.z + v3 * q.w;
  }
  acc = wave_reduce_add(acc);
  if (lane == 0) zf2[gw] = acc + bias[o];
}

// ---------------- head: per-block BN-f2 stats + 4 waves x 10 dots + log_softmax ----------------
__global__ __launch_bounds__(256) void head_kernel(const float* __restrict__ zf2,
                                                   const float* __restrict__ gf2,
                                                   const float* __restrict__ bef2,
                                                   const float* __restrict__ w,
                                                   const float* __restrict__ bias,
                                                   float* __restrict__ out) {
  int b = blockIdx.x, tid = threadIdx.x;
  int wv = tid >> 6, lane = tid & 63;
  __shared__ float ssf[256], shf[256], lg[40], red[2];
  {
    float s = 0.f, q = 0.f;
    for (int bb = 0; bb < 32; bb++) {
      float v = zf2[(size_t)bb * 256 + tid];
      s += v;
      q += v * v;
    }
    float m = s * (1.0f / 32.0f);
    float var = q * (1.0f / 32.0f) - m * m;
    float a = gf2[tid] / sqrtf(var + EPS_BN);
    ssf[tid] = a;
    shf[tid] = bef2[tid] - m * a;
  }
  __syncthreads();
  float4 z = ((const float4*)(zf2 + (size_t)b * 256))[lane];
  float4 s = ((const float4*)ssf)[lane];
  float4 h = ((const float4*)shf)[lane];
  float v0 = fmaxf(z.x * s.x + h.x, 0.f);
  float v1 = fmaxf(z.y * s.y + h.y, 0.f);
  float v2 = fmaxf(z.z * s.z + h.z, 0.f);
  float v3 = fmaxf(z.w * s.w + h.w, 0.f);
  for (int r = 0; r < 10; r++) {
    int o = wv * 10 + r;
    float4 q = ((const float4*)(w + (size_t)o * 256))[lane];
    float a = v0 * q.x + v1 * q.y + v2 * q.z + v3 * q.w;
    a = wave_reduce_add(a);
    if (lane == 0) lg[o] = a + bias[o];
  }
  __syncthreads();
  if (tid == 0) {
    float mx = -3.4e38f;
    for (int i = 0; i < 40; i++) mx = fmaxf(mx, lg[i]);
    float sum = 0.f;
    for (int i = 0; i < 40; i++) sum += expf(lg[i] - mx);
    red[0] = mx;
    red[1] = logf(sum);
  }
  __syncthreads();
  if (tid < 40) out[(size_t)b * 40 + tid] = lg[tid] - red[0] - red[1];
}

extern "C" void kernel_launch(void* const* d_in, const int* in_sizes, int n_in,
                              void* d_out, int out_size, void* d_ws, size_t ws_size,
                              hipStream_t stream) {
  const float* x    = (const float*)d_in[0];
  const float* c1w  = (const float*)d_in[1];
  const float* c1b  = (const float*)d_in[2];
  const float* g1   = (const float*)d_in[3];
  const float* be1  = (const float*)d_in[4];
  const float* c2w  = (const float*)d_in[5];
  const float* c2b  = (const float*)d_in[6];
  const float* g2   = (const float*)d_in[7];
  const float* be2  = (const float*)d_in[8];
  const float* c3w  = (const float*)d_in[9];
  const float* c3b  = (const float*)d_in[10];
  const float* g3   = (const float*)d_in[11];
  const float* be3  = (const float*)d_in[12];
  const float* f1w  = (const float*)d_in[13];
  const float* f1b  = (const float*)d_in[14];
  const float* gf1  = (const float*)d_in[15];
  const float* bef1 = (const float*)d_in[16];
  const float* f2w  = (const float*)d_in[17];
  const float* f2b  = (const float*)d_in[18];
  const float* gf2  = (const float*)d_in[19];
  const float* bef2 = (const float*)d_in[20];
  const float* ow   = (const float*)d_in[21];
  const float* ob   = (const float*)d_in[22];
  float* out = (float*)d_out;

  float* W = (float*)d_ws;
  float* pS     = W;                   // 524288
  float* pQ     = pS + 524288;
  float* pMx    = pQ + 524288;
  float* pMn    = pMx + 524288;
  float* part   = pMn + 524288;        // 131072 (BN1 partials 1024x64x2)
  float* part2  = part + 262144;       // 131072 (BN2 partials 512x128x2)
  float* pooled = part2 + 131072;      // 32768
  float* zf1    = pooled + 32768;      // 16384
  float* zf2    = zf1 + 16384;         // 8192
  float* s1     = zf2 + 8192;          // 64
  float* h1     = s1 + 64;
  float* s2     = h1 + 64;             // 128
  float* h2     = s2 + 128;
  float* sf1    = h2 + 128;            // 512
  float* hf1    = sf1 + 512;
  unsigned short* wbf  = (unsigned short*)(hf1 + 512);   // 131072 shorts (w3 bf16)
  unsigned short* w2bf = wbf + 131072;                   // 8192 shorts (w2 bf16)
  unsigned short* z1bf = w2bf + 8192;                    // 65536*64
  unsigned short* z2bf = z1bf + (size_t)BP * 64;         // 65536*128

  curv1_kernel<<<dim3(32, 33), 256, 0, stream>>>(x, c1w, c1b, c3w, c2w, wbf, w2bf, z1bf, part);
  bnfinP_kernel<64, 1024><<<64, 256, 0, stream>>>(part, g1, be1, s1, h1);
  gemm2_mfma_kernel<<<512, 256, 0, stream>>>(z1bf, s1, h1, w2bf, c2b, z2bf, part2);
  bnfinP_kernel<128, 512><<<128, 256, 0, stream>>>(part2, g2, be2, s2, h2);
  gemm3_mfma_kernel<<<512, 256, 0, stream>>>(z2bf, s2, h2, wbf, c3b, pS, pQ, pMx, pMn);
  bn3fin_pool_kernel<<<64, 256, 0, stream>>>(pS, pQ, pMx, pMn, g3, be3, pooled);
  fc1_kernel<<<4096, 256, 0, stream>>>(pooled, f1w, f1b, zf1);
  statsF_kernel<<<2, 256, 0, stream>>>(zf1, gf1, bef1, 512, sf1, hf1);
  fc2_kernel<<<2048, 256, 0, stream>>>(zf1, sf1, hf1, f2w, f2b, zf2);
  head_kernel<<<32, 256, 0, stream>>>(zf2, gf2, bef2, ow, ob, out);
}

// Round 16
// 126.116 us; speedup vs baseline: 1.0524x; 1.0004x over previous
//
#include <hip/hip_runtime.h>
#include <hip/hip_bf16.h>
#include <math.h>

#define EPS_BN 1e-5f

constexpr int BATCH = 32;
constexpr int NPTS  = 2048;
constexpr int BP    = BATCH * NPTS;   // 65536

using s16x8 = __attribute__((ext_vector_type(8))) short;
using u16x4 = __attribute__((ext_vector_type(4))) unsigned short;
using u32x4 = __attribute__((ext_vector_type(4))) unsigned;
using f32x4 = __attribute__((ext_vector_type(4))) float;

static __device__ __forceinline__ unsigned short f2bf(float f) {
  union { float f; unsigned u; } x{f};
  unsigned r = x.u + 0x7fffu + ((x.u >> 16) & 1u);  // RNE
  return (unsigned short)(r >> 16);
}
static __device__ __forceinline__ float bf2f(unsigned short s) {
  union { unsigned u; float f; } x;
  x.u = ((unsigned)s) << 16;
  return x.f;
}
static __device__ __forceinline__ unsigned pk2bf(float lo, float hi) {
  __hip_bfloat162 t = __float22bfloat162_rn(float2{lo, hi});
  unsigned r;
  __builtin_memcpy(&r, &t, 4);
  return r;
}

static __device__ __forceinline__ void gload_lds16(const void* g, void* l) {
  __builtin_amdgcn_global_load_lds((const __attribute__((address_space(1))) void*)g,
                                   (__attribute__((address_space(3))) void*)l, 16, 0, 0);
}

static __device__ __forceinline__ float wave_reduce_add(float v) {
#pragma unroll
  for (int off = 32; off > 0; off >>= 1) v += __shfl_xor(v, off);
  return v;
}

// keep-6-smallest, ASCENDING list, depth-1 branchless insert (1 min + 5 med3).
static __device__ __forceinline__ void ins6(float (&nn)[6], float c) {
  float b0 = fminf(nn[0], c);
  float b1 = __builtin_amdgcn_fmed3f(c, nn[1], nn[0]);
  float b2 = __builtin_amdgcn_fmed3f(c, nn[2], nn[1]);
  float b3 = __builtin_amdgcn_fmed3f(c, nn[3], nn[2]);
  float b4 = __builtin_amdgcn_fmed3f(c, nn[4], nn[3]);
  float b5 = __builtin_amdgcn_fmed3f(c, nn[5], nn[4]);
  nn[0] = b0; nn[1] = b1; nn[2] = b2; nn[3] = b3; nn[4] = b4; nn[5] = b5;
}

// ---------------- curvature + fused layer1 (+ weight-conversion plane y==32) ----------------
constexpr int CHP = 257;  // float4 stride per 256-pt chunk
__global__ __launch_bounds__(256) void curv1_kernel(const float* __restrict__ x,
                                                    const float* __restrict__ c1w,
                                                    const float* __restrict__ c1b,
                                                    const float* __restrict__ w3,
                                                    const float* __restrict__ w2,
                                                    unsigned short* __restrict__ w3bf,
                                                    unsigned short* __restrict__ w2bf,
                                                    unsigned short* __restrict__ z1bf,
                                                    float* __restrict__ part) {
  int tid = threadIdx.x;
  if (blockIdx.y == 32) {  // weight-conversion plane: 32 blocks, no barriers
    int g = blockIdx.x * 256 + tid;  // 0..8191
#pragma unroll
    for (int t = 0; t < 4; t++) {
      int gg = g + t * 8192;
      const float4 v = ((const float4*)w3)[gg];
      u16x4 a{f2bf(v.x), f2bf(v.y), f2bf(v.z), f2bf(v.w)};
      *(u16x4*)(w3bf + (size_t)gg * 4) = a;
    }
    if (g < 2048) {
      const float4 v = ((const float4*)w2)[g];
      u16x4 a{f2bf(v.x), f2bf(v.y), f2bf(v.z), f2bf(v.w)};
      *(u16x4*)(w2bf + (size_t)g * 4) = a;
    }
    return;
  }
  __shared__ float4 pts[8 * CHP];   // 32896 B
  __shared__ float wT[4 * 64], lb1[64], sfeat[64 * 4];
  __shared__ float ls[256], lq[256];
  int b = blockIdx.y;
  const float* xb = x + (size_t)b * NPTS * 3;
  {
    int k = tid >> 6, c = tid & 63;
    wT[k * 64 + c] = c1w[c * 4 + k];
    if (tid < 64) lb1[tid] = c1b[tid];
  }
#pragma unroll
  for (int k = 0; k < 8; k++) {
    int i = k * 256 + tid;
    float qx = xb[i * 3 + 0], qy = xb[i * 3 + 1], qz = xb[i * 3 + 2];
    pts[k * CHP + tid] = make_float4(qx, qy, qz, 0.5f * (qx * qx + qy * qy + qz * qz));
  }
  __syncthreads();
  int pr = tid >> 3;   // row-pair index 0..31
  int sub = tid & 7;   // chunk index
  int rA = blockIdx.x * 64 + pr * 2;
  int rB = rA + 1;
  float4 pA = pts[(rA >> 8) * CHP + (rA & 255)];
  float4 pB = pts[(rB >> 8) * CHP + (rB & 255)];
  float nnA[6], nnB[6];
#pragma unroll
  for (int j = 0; j < 6; j++) { nnA[j] = 3.4e38f; nnB[j] = 3.4e38f; }
  const float4* cp = pts + sub * CHP;
  for (int j = 0; j < 256; j += 4) {
    float4 q0 = cp[j + 0], q1 = cp[j + 1], q2 = cp[j + 2], q3 = cp[j + 3];
    ins6(nnA, fmaf(-pA.x, q0.x, fmaf(-pA.y, q0.y, fmaf(-pA.z, q0.z, q0.w))));
    ins6(nnB, fmaf(-pB.x, q0.x, fmaf(-pB.y, q0.y, fmaf(-pB.z, q0.z, q0.w))));
    ins6(nnA, fmaf(-pA.x, q1.x, fmaf(-pA.y, q1.y, fmaf(-pA.z, q1.z, q1.w))));
    ins6(nnB, fmaf(-pB.x, q1.x, fmaf(-pB.y, q1.y, fmaf(-pB.z, q1.z, q1.w))));
    ins6(nnA, fmaf(-pA.x, q2.x, fmaf(-pA.y, q2.y, fmaf(-pA.z, q2.z, q2.w))));
    ins6(nnB, fmaf(-pB.x, q2.x, fmaf(-pB.y, q2.y, fmaf(-pB.z, q2.z, q2.w))));
    ins6(nnA, fmaf(-pA.x, q3.x, fmaf(-pA.y, q3.y, fmaf(-pA.z, q3.z, q3.w))));
    ins6(nnB, fmaf(-pB.x, q3.x, fmaf(-pB.y, q3.y, fmaf(-pB.z, q3.z, q3.w))));
  }
#pragma unroll
  for (int m = 1; m <= 4; m <<= 1) {
    float oA[6], oB[6];
#pragma unroll
    for (int k = 0; k < 6; k++) { oA[k] = __shfl_xor(nnA[k], m); oB[k] = __shfl_xor(nnB[k], m); }
#pragma unroll
    for (int k = 0; k < 6; k++) { ins6(nnA, oA[k]); ins6(nnB, oB[k]); }
  }
  if (sub == 0) {
    float p2A = pA.x * pA.x + pA.y * pA.y + pA.z * pA.z;
    float p2B = pB.x * pB.x + pB.y * pB.y + pB.z * pB.z;
    float dmA = 0.f, dmB = 0.f;
#pragma unroll
    for (int i = 1; i < 6; i++) {
      dmA += sqrtf(fmaxf(fmaf(2.f, nnA[i], p2A), 0.f));
      dmB += sqrtf(fmaxf(fmaf(2.f, nnB[i], p2B), 0.f));
    }
    int lrA = pr * 2;
    sfeat[lrA * 4 + 0] = pA.x;
    sfeat[lrA * 4 + 1] = pA.y;
    sfeat[lrA * 4 + 2] = pA.z;
    sfeat[lrA * 4 + 3] = 1.0f / (1e-8f + 0.2f * dmA);
    sfeat[lrA * 4 + 4] = pB.x;
    sfeat[lrA * 4 + 5] = pB.y;
    sfeat[lrA * 4 + 6] = pB.z;
    sfeat[lrA * 4 + 7] = 1.0f / (1e-8f + 0.2f * dmB);
  }
  __syncthreads();
  {
    int c = tid & 63, rg = tid >> 6;
    float w0 = wT[c], w1 = wT[64 + c], w2v = wT[128 + c], w3v = wT[192 + c];
    float bb = lb1[c];
    int growbase = b * NPTS + blockIdx.x * 64;
    float s = 0.f, q = 0.f;
#pragma unroll
    for (int i = 0; i < 16; i++) {
      int lr = rg * 16 + i;
      float4 f = *(const float4*)(sfeat + lr * 4);
      float acc = bb + f.x * w0 + f.y * w1 + f.z * w2v + f.w * w3v;
      s += acc;
      q += acc * acc;
      z1bf[(size_t)(growbase + lr) * 64 + c] = f2bf(acc);
    }
    ls[tid] = s;
    lq[tid] = q;
  }
  __syncthreads();
  if (tid < 64) {
    float ss = 0.f, qq = 0.f;
#pragma unroll
    for (int i = 0; i < 4; i++) { ss += ls[i * 64 + tid]; qq += lq[i * 64 + tid]; }
    size_t bid = (size_t)b * 32 + blockIdx.x;
    part[(bid * 64 + tid) * 2 + 0] = ss;
    part[(bid * 64 + tid) * 2 + 1] = qq;
  }
}

// ---------------- generic BN finalize from P partials ----------------
template <int C, int P>
__global__ __launch_bounds__(256) void bnfinP_kernel(const float* __restrict__ part,
                                                     const float* __restrict__ g,
                                                     const float* __restrict__ be,
                                                     float* __restrict__ scale,
                                                     float* __restrict__ shift) {
  int c = blockIdx.x, tid = threadIdx.x;
  float s = 0.f, q = 0.f;
  for (int i = tid; i < P; i += 256) {
    s += part[((size_t)i * C + c) * 2 + 0];
    q += part[((size_t)i * C + c) * 2 + 1];
  }
  __shared__ float ls[256], lq[256];
  ls[tid] = s; lq[tid] = q;
  __syncthreads();
  for (int off = 128; off > 0; off >>= 1) {
    if (tid < off) { ls[tid] += ls[tid + off]; lq[tid] += lq[tid + off]; }
    __syncthreads();
  }
  if (tid == 0) {
    float m = ls[0] * (1.0f / 65536.0f);
    float v = lq[0] * (1.0f / 65536.0f) - m * m;
    float a = g[c] / sqrtf(v + EPS_BN);
    scale[c] = a;
    shift[c] = be[c] - m * a;
  }
}

// ---------------- layer2 MFMA: relu(bn1(z1bf)) @ W2^T + b2 -> z2bf + BN2 stats ----------------
// XCD-chunked panel mapping MATCHES gemm3's: panel rblk on XCD rblk/64, so z2bf
// stays in that XCD's private L2 (2MB/XCD of 4MB) across the gemm2->gemm3 seam.
__global__ __launch_bounds__(256) void gemm2_mfma_kernel(const unsigned short* __restrict__ z1bf,
                                                         const float* __restrict__ s1,
                                                         const float* __restrict__ h1,
                                                         const unsigned short* __restrict__ w2bf,
                                                         const float* __restrict__ bias2,
                                                         unsigned short* __restrict__ z2bf,
                                                         float* __restrict__ part2) {
  __shared__ char lds[33280];  // A @0 (16KB), B @16384 (16KB), s1h1 @32768
  float* ls1 = (float*)(lds + 32768);
  float* lh1 = ls1 + 64;
  int tid = threadIdx.x;
  int bid = blockIdx.x;
  int rblk = (bid & 7) * 64 + (bid >> 3);   // same mapping as gemm3
  int row0 = rblk * 128;
  if (tid < 64) { ls1[tid] = s1[tid]; lh1[tid] = h1[tid]; }

  s16x8 araw[4], braw[4];
#pragma unroll
  for (int i = 0; i < 4; i++) {
    int L = tid + 256 * i;
    araw[i] = *(const s16x8*)(z1bf + (size_t)row0 * 64 + (size_t)L * 8);
    braw[i] = *(const s16x8*)(w2bf + (size_t)L * 8);
  }
  __syncthreads();

#pragma unroll
  for (int i = 0; i < 4; i++) {
    int L = tid + 256 * i;
    int row = L >> 3, grp = L & 7, k0 = grp * 8;
    float4 sA = *(const float4*)(ls1 + k0);
    float4 sB = *(const float4*)(ls1 + k0 + 4);
    float4 hA = *(const float4*)(lh1 + k0);
    float4 hB = *(const float4*)(lh1 + k0 + 4);
    float v0 = fmaxf(bf2f((unsigned short)araw[i][0]) * sA.x + hA.x, 0.f);
    float v1 = fmaxf(bf2f((unsigned short)araw[i][1]) * sA.y + hA.y, 0.f);
    float v2 = fmaxf(bf2f((unsigned short)araw[i][2]) * sA.z + hA.z, 0.f);
    float v3 = fmaxf(bf2f((unsigned short)araw[i][3]) * sA.w + hA.w, 0.f);
    float v4 = fmaxf(bf2f((unsigned short)araw[i][4]) * sB.x + hB.x, 0.f);
    float v5 = fmaxf(bf2f((unsigned short)araw[i][5]) * sB.y + hB.y, 0.f);
    float v6 = fmaxf(bf2f((unsigned short)araw[i][6]) * sB.z + hB.z, 0.f);
    float v7 = fmaxf(bf2f((unsigned short)araw[i][7]) * sB.w + hB.w, 0.f);
    u32x4 pa = {pk2bf(v0, v1), pk2bf(v2, v3), pk2bf(v4, v5), pk2bf(v6, v7)};
    *(u32x4*)(lds + row * 128 + ((grp ^ (row & 7)) << 4)) = pa;
    *(s16x8*)(lds + 16384 + row * 128 + ((grp ^ (row & 7)) << 4)) = braw[i];
  }
  __syncthreads();

  int w = tid >> 6, lane = tid & 63;
  int wm = w >> 1, wn = w & 1;
  int lrow = lane & 15, lg = lane >> 4;
  int sw = (lrow & 7) << 4;
  f32x4 acc[4][4] = {};
#pragma unroll
  for (int kstep = 0; kstep < 2; kstep++) {
    s16x8 a[4], bfr[4];
#pragma unroll
    for (int m = 0; m < 4; m++) {
      int row = wm * 64 + m * 16 + lrow;
      int byte = row * 128 + ((kstep * 64 + lg * 16) ^ sw);
      a[m] = *(const s16x8*)(lds + byte);
    }
#pragma unroll
    for (int n = 0; n < 4; n++) {
      int col = wn * 64 + n * 16 + lrow;
      int byte = 16384 + col * 128 + ((kstep * 64 + lg * 16) ^ sw);
      bfr[n] = *(const s16x8*)(lds + byte);
    }
#pragma unroll
    for (int m = 0; m < 4; m++)
#pragma unroll
      for (int n = 0; n < 4; n++)
        acc[m][n] = __builtin_amdgcn_mfma_f32_16x16x32_bf16(a[m], bfr[n], acc[m][n], 0, 0, 0);
  }
  __syncthreads();

  float* sS = (float*)lds;
  float* sQ = sS + 256;
#pragma unroll
  for (int n = 0; n < 4; n++) {
    int col = wn * 64 + n * 16 + lrow;
    float bb = bias2[col];
    float s = 0.f, q = 0.f;
#pragma unroll
    for (int m = 0; m < 4; m++) {
#pragma unroll
      for (int r = 0; r < 4; r++) {
        float v = acc[m][n][r] + bb;
        s += v;
        q += v * v;
        int row = row0 + wm * 64 + m * 16 + lg * 4 + r;
        z2bf[(size_t)row * 128 + col] = f2bf(v);
      }
    }
    s += __shfl_xor(s, 16); s += __shfl_xor(s, 32);
    q += __shfl_xor(q, 16); q += __shfl_xor(q, 32);
    if (lane < 16) {
      int cidx = wn * 64 + n * 16 + lane;
      sS[wm * 128 + cidx] = s;
      sQ[wm * 128 + cidx] = q;
    }
  }
  __syncthreads();
  if (tid < 128) {
    part2[((size_t)rblk * 128 + tid) * 2 + 0] = sS[tid] + sS[128 + tid];
    part2[((size_t)rblk * 128 + tid) * 2 + 1] = sQ[tid] + sQ[128 + tid];
  }
}

// ---------------- layer3 MFMA: one block per 128-row panel, loop over 8 col-blocks ----------------
__global__ __launch_bounds__(256) void gemm3_mfma_kernel(const unsigned short* __restrict__ z2bf,
                                                         const float* __restrict__ s2,
                                                         const float* __restrict__ h2,
                                                         const unsigned short* __restrict__ wbf,
                                                         const float* __restrict__ bias3,
                                                         float* __restrict__ pS,
                                                         float* __restrict__ pQ,
                                                         float* __restrict__ pMx,
                                                         float* __restrict__ pMn) {
  __shared__ char lds[70656];  // A[0,32768) B[32768,65536) scratch[65536,69632) s2h2[69632,70656)
  float* ls2 = (float*)(lds + 69632);
  float* lh2 = ls2 + 128;
  int tid = threadIdx.x;
  int w = tid >> 6, lane = tid & 63;
  int bid = blockIdx.x;                 // 512 blocks, XCD-chunked
  int rblk = (bid & 7) * 64 + (bid >> 3);
  int row0 = rblk * 128;

  if (tid < 128) { ls2[tid] = s2[tid]; lh2[tid] = h2[tid]; }
  s16x8 araw[8];
#pragma unroll
  for (int i = 0; i < 8; i++) {
    int L = tid + 256 * i;
    int row = L >> 4, gc = L & 15;
    araw[i] = *(const s16x8*)(z2bf + (size_t)(row0 + row) * 128 + gc * 8);
  }
  __syncthreads();
#pragma unroll
  for (int i = 0; i < 8; i++) {
    int L = tid + 256 * i;
    int row = L >> 4, gc = L & 15, k0 = gc * 8;
    float4 sA = *(const float4*)(ls2 + k0);
    float4 sB = *(const float4*)(ls2 + k0 + 4);
    float4 hA = *(const float4*)(lh2 + k0);
    float4 hB = *(const float4*)(lh2 + k0 + 4);
    float v0 = fmaxf(bf2f((unsigned short)araw[i][0]) * sA.x + hA.x, 0.f);
    float v1 = fmaxf(bf2f((unsigned short)araw[i][1]) * sA.y + hA.y, 0.f);
    float v2 = fmaxf(bf2f((unsigned short)araw[i][2]) * sA.z + hA.z, 0.f);
    float v3 = fmaxf(bf2f((unsigned short)araw[i][3]) * sA.w + hA.w, 0.f);
    float v4 = fmaxf(bf2f((unsigned short)araw[i][4]) * sB.x + hB.x, 0.f);
    float v5 = fmaxf(bf2f((unsigned short)araw[i][5]) * sB.y + hB.y, 0.f);
    float v6 = fmaxf(bf2f((unsigned short)araw[i][6]) * sB.z + hB.z, 0.f);
    float v7 = fmaxf(bf2f((unsigned short)araw[i][7]) * sB.w + hB.w, 0.f);
    u32x4 pa = {pk2bf(v0, v1), pk2bf(v2, v3), pk2bf(v4, v5), pk2bf(v6, v7)};
    *(u32x4*)(lds + row * 256 + ((gc ^ (row & 7)) << 4)) = pa;
  }

  int wm = w >> 1, wn = w & 1;
  int lrow = lane & 15, lg = lane >> 4;
  int sw = (lrow & 7) << 4;
  float* sS = (float*)(lds + 65536);   // [2][128]
  float* sQ = sS + 256;
  float* sMx = sQ + 256;
  float* sMn = sMx + 256;

  for (int cblk = 0; cblk < 8; cblk++) {
    int col0 = cblk * 128;
#pragma unroll
    for (int i = 0; i < 8; i++) {
      int ldsoff = w * 8192 + i * 1024;
      int lin = ldsoff + lane * 16;
      int row = lin >> 8;
      int gc = (lin >> 4) & 15;
      int gcl = gc ^ (row & 7);
      gload_lds16(wbf + (size_t)(col0 + row) * 128 + gcl * 8, &lds[32768 + ldsoff]);
    }
    __syncthreads();

    f32x4 acc[4][4] = {};
#pragma unroll
    for (int kstep = 0; kstep < 4; kstep++) {
      s16x8 a[4], b[4];
#pragma unroll
      for (int m = 0; m < 4; m++) {
        int row = wm * 64 + m * 16 + lrow;
        int byte = row * 256 + ((kstep * 64 + lg * 16) ^ sw);
        a[m] = *(const s16x8*)(lds + byte);
      }
#pragma unroll
      for (int n = 0; n < 4; n++) {
        int col = wn * 64 + n * 16 + lrow;
        int byte = 32768 + col * 256 + ((kstep * 64 + lg * 16) ^ sw);
        b[n] = *(const s16x8*)(lds + byte);
      }
#pragma unroll
      for (int m = 0; m < 4; m++)
#pragma unroll
        for (int n = 0; n < 4; n++)
          acc[m][n] = __builtin_amdgcn_mfma_f32_16x16x32_bf16(a[m], b[n], acc[m][n], 0, 0, 0);
    }

#pragma unroll
    for (int n = 0; n < 4; n++) {
      float v[16];
      float s = 0.f, q = 0.f;
#pragma unroll
      for (int m = 0; m < 4; m++)
#pragma unroll
        for (int r = 0; r < 4; r++) {
          float t = acc[m][n][r];
          v[m * 4 + r] = t;
          s += t;
          q = fmaf(t, t, q);
        }
      float mx = fmaxf(fmaxf(fmaxf(fmaxf(v[0], v[1]), v[2]),
                             fmaxf(fmaxf(v[3], v[4]), v[5])),
                       fmaxf(fmaxf(fmaxf(v[6], v[7]), v[8]),
                             fmaxf(fmaxf(v[9], v[10]), v[11])));
      mx = fmaxf(mx, fmaxf(fmaxf(v[12], v[13]), fmaxf(v[14], v[15])));
      float mn = fminf(fminf(fminf(fminf(v[0], v[1]), v[2]),
                             fminf(fminf(v[3], v[4]), v[5])),
                       fminf(fminf(fminf(v[6], v[7]), v[8]),
                             fminf(fminf(v[9], v[10]), v[11])));
      mn = fminf(mn, fminf(fminf(v[12], v[13]), fminf(v[14], v[15])));
      s += __shfl_xor(s, 16); s += __shfl_xor(s, 32);
      q += __shfl_xor(q, 16); q += __shfl_xor(q, 32);
      mx = fmaxf(mx, __shfl_xor(mx, 16)); mx = fmaxf(mx, __shfl_xor(mx, 32));
      mn = fminf(mn, __shfl_xor(mn, 16)); mn = fminf(mn, __shfl_xor(mn, 32));
      if (lane < 16) {
        int cidx = wn * 64 + n * 16 + lane;
        sS[wm * 128 + cidx] = s;
        sQ[wm * 128 + cidx] = q;
        sMx[wm * 128 + cidx] = mx;
        sMn[wm * 128 + cidx] = mn;
      }
    }
    __syncthreads();
    if (tid < 128) {
      float bcol = bias3[col0 + tid];
      float S = sS[tid] + sS[128 + tid];
      float Q = sQ[tid] + sQ[128 + tid];
      size_t o = (size_t)rblk * 1024 + col0 + tid;
      pS[o] = S + 128.f * bcol;
      pQ[o] = Q + 2.f * bcol * S + 128.f * bcol * bcol;
      pMx[o] = fmaxf(sMx[tid], sMx[128 + tid]) + bcol;
      pMn[o] = fminf(sMn[tid], sMn[128 + tid]) + bcol;
    }
    __syncthreads();
  }
}

// ---------------- bn3 finalize + masked max-pool ----------------
__global__ __launch_bounds__(256) void bn3fin_pool_kernel(const float* __restrict__ pS,
                                                          const float* __restrict__ pQ,
                                                          const float* __restrict__ pMx,
                                                          const float* __restrict__ pMn,
                                                          const float* __restrict__ g,
                                                          const float* __restrict__ be,
                                                          float* __restrict__ pooled) {
  int tid = threadIdx.x;
  int chl = tid & 15, grp = tid >> 4;
  int c = blockIdx.x * 16 + chl;
  float s = 0.f, q = 0.f;
  for (int i = grp; i < 512; i += 16) {
    s += pS[(size_t)i * 1024 + c];
    q += pQ[(size_t)i * 1024 + c];
  }
  __shared__ float ls[256], lq[256], sa[16], sc[16];
  ls[chl * 16 + grp] = s;
  lq[chl * 16 + grp] = q;
  __syncthreads();
  if (tid < 16) {
    float ss = 0.f, qq = 0.f;
#pragma unroll
    for (int i = 0; i < 16; i++) { ss += ls[tid * 16 + i]; qq += lq[tid * 16 + i]; }
    float m = ss * (1.0f / 65536.0f);
    float v = qq * (1.0f / 65536.0f) - m * m;
    float a = g[blockIdx.x * 16 + tid] / sqrtf(v + EPS_BN);
    sa[tid] = a;
    sc[tid] = be[blockIdx.x * 16 + tid] - m * a;
  }
  __syncthreads();
  for (int idx = tid; idx < 512; idx += 256) {
    int b = idx >> 4, l = idx & 15;
    int cc = blockIdx.x * 16 + l;
    float mx = -3.4e38f, mn = 3.4e38f;
    for (int i = 0; i < 16; i++) {
      mx = fmaxf(mx, pMx[(size_t)(b * 16 + i) * 1024 + cc]);
      mn = fminf(mn, pMn[(size_t)(b * 16 + i) * 1024 + cc]);
    }
    float a = sa[l];
    float v = (a > 0.f) ? (a * mx + sc[l]) : (a * mn + sc[l]);
    pooled[(size_t)b * 1024 + cc] = fmaxf(v, 0.f);
  }
}

// ---------------- fc1: wave-per-output ----------------
__global__ __launch_bounds__(256) void fc1_kernel(const float* __restrict__ pooled,
                                                  const float* __restrict__ w,
                                                  const float* __restrict__ bias,
                                                  float* __restrict__ zf1) {
  int gw = blockIdx.x * 4 + (threadIdx.x >> 6);
  int lane = threadIdx.x & 63;
  int b = gw >> 9, o = gw & 511;
  const float4* pr = (const float4*)(pooled + (size_t)b * 1024);
  const float4* wr = (const float4*)(w + (size_t)o * 1024);
  float acc = 0.f;
#pragma unroll
  for (int i = 0; i < 4; i++) {
    int k = lane + i * 64;
    float4 p = pr[k], q = wr[k];
    acc += p.x * q.x + p.y * q.y + p.z * q.z + p.w * q.w;
  }
  acc = wave_reduce_add(acc);
  if (lane == 0) zf1[gw] = acc + bias[o];
}

__global__ __launch_bounds__(256) void statsF_kernel(const float* __restrict__ z,
                                                     const float* __restrict__ g,
                                                     const float* __restrict__ be, int C,
                                                     float* __restrict__ scale,
                                                     float* __restrict__ shift) {
  int c = blockIdx.x * 256 + threadIdx.x;
  if (c >= C) return;
  float s = 0.f, q = 0.f;
  for (int b = 0; b < 32; b++) {
    float v = z[(size_t)b * C + c];
    s += v;
    q += v * v;
  }
  float m = s * (1.0f / 32.0f);
  float v = q * (1.0f / 32.0f) - m * m;
  float a = g[c] / sqrtf(v + EPS_BN);
  scale[c] = a;
  shift[c] = be[c] - m * a;
}

// ---------------- fc2: wave-per-output ----------------
__global__ __launch_bounds__(256) void fc2_kernel(const float* __restrict__ zf1,
                                                  const float* __restrict__ sf1,
                                                  const float* __restrict__ hf1,
                                                  const float* __restrict__ w,
                                                  const float* __restrict__ bias,
                                                  float* __restrict__ zf2) {
  int gw = blockIdx.x * 4 + (threadIdx.x >> 6);
  int lane = threadIdx.x & 63;
  int b = gw >> 8, o = gw & 255;
  const float4* zr = (const float4*)(zf1 + (size_t)b * 512);
  const float4* sr = (const float4*)sf1;
  const float4* hr = (const float4*)hf1;
  const float4* wr = (const float4*)(w + (size_t)o * 512);
  float acc = 0.f;
#pragma unroll
  for (int i = 0; i < 2; i++) {
    int k = lane + i * 64;
    float4 z = zr[k], s = sr[k], h = hr[k], q = wr[k];
    float v0 = fmaxf(z.x * s.x + h.x, 0.f);
    float v1 = fmaxf(z.y * s.y + h.y, 0.f);
    float v2 = fmaxf(z.z * s.z + h.z, 0.f);
    float v3 = fmaxf(z.w * s.w + h.w, 0.f);
    acc += v0 * q.x + v1 * q.y + v2 * q.z + v3 * q.w;
  }
  acc = wave_reduce_add(acc);
  if (lane == 0) zf2[gw] = acc + bias[o];
}

// ---------------- head: per-block BN-f2 stats + 4 waves x 10 dots + log_softmax ----------------
__global__ __launch_bounds__(256) void head_kernel(const float* __restrict__ zf2,
                                                   const float* __restrict__ gf2,
                                                   const float* __restrict__ bef2,
                                                   const float* __restrict__ w,
                                                   const float* __restrict__ bias,
                                                   float* __restrict__ out) {
  int b = blockIdx.x, tid = threadIdx.x;
  int wv = tid >> 6, lane = tid & 63;
  __shared__ float ssf[256], shf[256], lg[40], red[2];
  {
    float s = 0.f, q = 0.f;
    for (int bb = 0; bb < 32; bb++) {
      float v = zf2[(size_t)bb * 256 + tid];
      s += v;
      q += v * v;
    }
    float m = s * (1.0f / 32.0f);
    float var = q * (1.0f / 32.0f) - m * m;
    float a = gf2[tid] / sqrtf(var + EPS_BN);
    ssf[tid] = a;
    shf[tid] = bef2[tid] - m * a;
  }
  __syncthreads();
  float4 z = ((const float4*)(zf2 + (size_t)b * 256))[lane];
  float4 s = ((const float4*)ssf)[lane];
  float4 h = ((const float4*)shf)[lane];
  float v0 = fmaxf(z.x * s.x + h.x, 0.f);
  float v1 = fmaxf(z.y * s.y + h.y, 0.f);
  float v2 = fmaxf(z.z * s.z + h.z, 0.f);
  float v3 = fmaxf(z.w * s.w + h.w, 0.f);
  for (int r = 0; r < 10; r++) {
    int o = wv * 10 + r;
    float4 q = ((const float4*)(w + (size_t)o * 256))[lane];
    float a = v0 * q.x + v1 * q.y + v2 * q.z + v3 * q.w;
    a = wave_reduce_add(a);
    if (lane == 0) lg[o] = a + bias[o];
  }
  __syncthreads();
  if (tid == 0) {
    float mx = -3.4e38f;
    for (int i = 0; i < 40; i++) mx = fmaxf(mx, lg[i]);
    float sum = 0.f;
    for (int i = 0; i < 40; i++) sum += expf(lg[i] - mx);
    red[0] = mx;
    red[1] = logf(sum);
  }
  __syncthreads();
  if (tid < 40) out[(size_t)b * 40 + tid] = lg[tid] - red[0] - red[1];
}

extern "C" void kernel_launch(void* const* d_in, const int* in_sizes, int n_in,
                              void* d_out, int out_size, void* d_ws, size_t ws_size,
                              hipStream_t stream) {
  const float* x    = (const float*)d_in[0];
  const float* c1w  = (const float*)d_in[1];
  const float* c1b  = (const float*)d_in[2];
  const float* g1   = (const float*)d_in[3];
  const float* be1  = (const float*)d_in[4];
  const float* c2w  = (const float*)d_in[5];
  const float* c2b  = (const float*)d_in[6];
  const float* g2   = (const float*)d_in[7];
  const float* be2  = (const float*)d_in[8];
  const float* c3w  = (const float*)d_in[9];
  const float* c3b  = (const float*)d_in[10];
  const float* g3   = (const float*)d_in[11];
  const float* be3  = (const float*)d_in[12];
  const float* f1w  = (const float*)d_in[13];
  const float* f1b  = (const float*)d_in[14];
  const float* gf1  = (const float*)d_in[15];
  const float* bef1 = (const float*)d_in[16];
  const float* f2w  = (const float*)d_in[17];
  const float* f2b  = (const float*)d_in[18];
  const float* gf2  = (const float*)d_in[19];
  const float* bef2 = (const float*)d_in[20];
  const float* ow   = (const float*)d_in[21];
  const float* ob   = (const float*)d_in[22];
  float* out = (float*)d_out;

  float* W = (float*)d_ws;
  float* pS     = W;                   // 524288
  float* pQ     = pS + 524288;
  float* pMx    = pQ + 524288;
  float* pMn    = pMx + 524288;
  float* part   = pMn + 524288;        // 131072 (BN1 partials 1024x64x2)
  float* part2  = part + 262144;       // 131072 (BN2 partials 512x128x2)
  float* pooled = part2 + 131072;      // 32768
  float* zf1    = pooled + 32768;      // 16384
  float* zf2    = zf1 + 16384;         // 8192
  float* s1     = zf2 + 8192;          // 64
  float* h1     = s1 + 64;
  float* s2     = h1 + 64;             // 128
  float* h2     = s2 + 128;
  float* sf1    = h2 + 128;            // 512
  float* hf1    = sf1 + 512;
  unsigned short* wbf  = (unsigned short*)(hf1 + 512);   // 131072 shorts (w3 bf16)
  unsigned short* w2bf = wbf + 131072;                   // 8192 shorts (w2 bf16)
  unsigned short* z1bf = w2bf + 8192;                    // 65536*64
  unsigned short* z2bf = z1bf + (size_t)BP * 64;         // 65536*128

  curv1_kernel<<<dim3(32, 33), 256, 0, stream>>>(x, c1w, c1b, c3w, c2w, wbf, w2bf, z1bf, part);
  bnfinP_kernel<64, 1024><<<64, 256, 0, stream>>>(part, g1, be1, s1, h1);
  gemm2_mfma_kernel<<<512, 256, 0, stream>>>(z1bf, s1, h1, w2bf, c2b, z2bf, part2);
  bnfinP_kernel<128, 512><<<128, 256, 0, stream>>>(part2, g2, be2, s2, h2);
  gemm3_mfma_kernel<<<512, 256, 0, stream>>>(z2bf, s2, h2, wbf, c3b, pS, pQ, pMx, pMn);
  bn3fin_pool_kernel<<<64, 256, 0, stream>>>(pS, pQ, pMx, pMn, g3, be3, pooled);
  fc1_kernel<<<4096, 256, 0, stream>>>(pooled, f1w, f1b, zf1);
  statsF_kernel<<<2, 256, 0, stream>>>(zf1, gf1, bef1, 512, sf1, hf1);
  fc2_kernel<<<2048, 256, 0, stream>>>(zf1, sf1, hf1, f2w, f2b, zf2);
  head_kernel<<<32, 256, 0, stream>>>(zf2, gf2, bef2, ow, ob, out);
}

// Round 17
// 124.838 us; speedup vs baseline: 1.0631x; 1.0102x over previous
//
#include <hip/hip_runtime.h>
#include <hip/hip_bf16.h>
#include <math.h>

#define EPS_BN 1e-5f

constexpr int BATCH = 32;
constexpr int NPTS  = 2048;
constexpr int BP    = BATCH * NPTS;   // 65536

using s16x8 = __attribute__((ext_vector_type(8))) short;
using u16x4 = __attribute__((ext_vector_type(4))) unsigned short;
using u32x4 = __attribute__((ext_vector_type(4))) unsigned;
using f32x4 = __attribute__((ext_vector_type(4))) float;

static __device__ __forceinline__ unsigned short f2bf(float f) {
  union { float f; unsigned u; } x{f};
  unsigned r = x.u + 0x7fffu + ((x.u >> 16) & 1u);  // RNE
  return (unsigned short)(r >> 16);
}
static __device__ __forceinline__ float bf2f(unsigned short s) {
  union { unsigned u; float f; } x;
  x.u = ((unsigned)s) << 16;
  return x.f;
}
static __device__ __forceinline__ unsigned pk2bf(float lo, float hi) {
  __hip_bfloat162 t = __float22bfloat162_rn(float2{lo, hi});
  unsigned r;
  __builtin_memcpy(&r, &t, 4);
  return r;
}

static __device__ __forceinline__ void gload_lds16(const void* g, void* l) {
  __builtin_amdgcn_global_load_lds((const __attribute__((address_space(1))) void*)g,
                                   (__attribute__((address_space(3))) void*)l, 16, 0, 0);
}

static __device__ __forceinline__ float wave_reduce_add(float v) {
#pragma unroll
  for (int off = 32; off > 0; off >>= 1) v += __shfl_xor(v, off);
  return v;
}

// keep-6-smallest, ASCENDING list, depth-1 branchless insert (1 min + 5 med3).
static __device__ __forceinline__ void ins6(float (&nn)[6], float c) {
  float b0 = fminf(nn[0], c);
  float b1 = __builtin_amdgcn_fmed3f(c, nn[1], nn[0]);
  float b2 = __builtin_amdgcn_fmed3f(c, nn[2], nn[1]);
  float b3 = __builtin_amdgcn_fmed3f(c, nn[3], nn[2]);
  float b4 = __builtin_amdgcn_fmed3f(c, nn[4], nn[3]);
  float b5 = __builtin_amdgcn_fmed3f(c, nn[5], nn[4]);
  nn[0] = b0; nn[1] = b1; nn[2] = b2; nn[3] = b3; nn[4] = b4; nn[5] = b5;
}

// ---------------- curvature + fused layer1 (+ weight-conversion plane y==32) ----------------
constexpr int CHP = 257;  // float4 stride per 256-pt chunk
__global__ __launch_bounds__(256) void curv1_kernel(const float* __restrict__ x,
                                                    const float* __restrict__ c1w,
                                                    const float* __restrict__ c1b,
                                                    const float* __restrict__ w3,
                                                    const float* __restrict__ w2,
                                                    unsigned short* __restrict__ w3bf,
                                                    unsigned short* __restrict__ w2bf,
                                                    unsigned short* __restrict__ z1bf,
                                                    float* __restrict__ part) {
  int tid = threadIdx.x;
  if (blockIdx.y == 32) {  // weight-conversion plane: 32 blocks, no barriers
    int g = blockIdx.x * 256 + tid;  // 0..8191
#pragma unroll
    for (int t = 0; t < 4; t++) {
      int gg = g + t * 8192;
      const float4 v = ((const float4*)w3)[gg];
      u16x4 a{f2bf(v.x), f2bf(v.y), f2bf(v.z), f2bf(v.w)};
      *(u16x4*)(w3bf + (size_t)gg * 4) = a;
    }
    if (g < 2048) {
      const float4 v = ((const float4*)w2)[g];
      u16x4 a{f2bf(v.x), f2bf(v.y), f2bf(v.z), f2bf(v.w)};
      *(u16x4*)(w2bf + (size_t)g * 4) = a;
    }
    return;
  }
  __shared__ float4 pts[8 * CHP];   // 32896 B
  __shared__ float wT[4 * 64], lb1[64], sfeat[64 * 4];
  __shared__ float ls[256], lq[256];
  int b = blockIdx.y;
  const float* xb = x + (size_t)b * NPTS * 3;
  {
    int k = tid >> 6, c = tid & 63;
    wT[k * 64 + c] = c1w[c * 4 + k];
    if (tid < 64) lb1[tid] = c1b[tid];
  }
#pragma unroll
  for (int k = 0; k < 8; k++) {
    int i = k * 256 + tid;
    float qx = xb[i * 3 + 0], qy = xb[i * 3 + 1], qz = xb[i * 3 + 2];
    pts[k * CHP + tid] = make_float4(qx, qy, qz, 0.5f * (qx * qx + qy * qy + qz * qz));
  }
  __syncthreads();
  int pr = tid >> 3;   // row-pair index 0..31
  int sub = tid & 7;   // chunk index
  int rA = blockIdx.x * 64 + pr * 2;
  int rB = rA + 1;
  float4 pA = pts[(rA >> 8) * CHP + (rA & 255)];
  float4 pB = pts[(rB >> 8) * CHP + (rB & 255)];
  float nnA[6], nnB[6];
#pragma unroll
  for (int j = 0; j < 6; j++) { nnA[j] = 3.4e38f; nnB[j] = 3.4e38f; }
  const float4* cp = pts + sub * CHP;
  // unroll-8: 28 of every 32 ds_read addresses fold to compile-time offsets on
  // one base register; loop bookkeeping amortized 8x (curv is issue-count-bound).
#pragma unroll 8
  for (int j = 0; j < 256; j += 4) {
    float4 q0 = cp[j + 0], q1 = cp[j + 1], q2 = cp[j + 2], q3 = cp[j + 3];
    ins6(nnA, fmaf(-pA.x, q0.x, fmaf(-pA.y, q0.y, fmaf(-pA.z, q0.z, q0.w))));
    ins6(nnB, fmaf(-pB.x, q0.x, fmaf(-pB.y, q0.y, fmaf(-pB.z, q0.z, q0.w))));
    ins6(nnA, fmaf(-pA.x, q1.x, fmaf(-pA.y, q1.y, fmaf(-pA.z, q1.z, q1.w))));
    ins6(nnB, fmaf(-pB.x, q1.x, fmaf(-pB.y, q1.y, fmaf(-pB.z, q1.z, q1.w))));
    ins6(nnA, fmaf(-pA.x, q2.x, fmaf(-pA.y, q2.y, fmaf(-pA.z, q2.z, q2.w))));
    ins6(nnB, fmaf(-pB.x, q2.x, fmaf(-pB.y, q2.y, fmaf(-pB.z, q2.z, q2.w))));
    ins6(nnA, fmaf(-pA.x, q3.x, fmaf(-pA.y, q3.y, fmaf(-pA.z, q3.z, q3.w))));
    ins6(nnB, fmaf(-pB.x, q3.x, fmaf(-pB.y, q3.y, fmaf(-pB.z, q3.z, q3.w))));
  }
#pragma unroll
  for (int m = 1; m <= 4; m <<= 1) {
    float oA[6], oB[6];
#pragma unroll
    for (int k = 0; k < 6; k++) { oA[k] = __shfl_xor(nnA[k], m); oB[k] = __shfl_xor(nnB[k], m); }
#pragma unroll
    for (int k = 0; k < 6; k++) { ins6(nnA, oA[k]); ins6(nnB, oB[k]); }
  }
  if (sub == 0) {
    float p2A = pA.x * pA.x + pA.y * pA.y + pA.z * pA.z;
    float p2B = pB.x * pB.x + pB.y * pB.y + pB.z * pB.z;
    float dmA = 0.f, dmB = 0.f;
#pragma unroll
    for (int i = 1; i < 6; i++) {
      dmA += sqrtf(fmaxf(fmaf(2.f, nnA[i], p2A), 0.f));
      dmB += sqrtf(fmaxf(fmaf(2.f, nnB[i], p2B), 0.f));
    }
    int lrA = pr * 2;
    sfeat[lrA * 4 + 0] = pA.x;
    sfeat[lrA * 4 + 1] = pA.y;
    sfeat[lrA * 4 + 2] = pA.z;
    sfeat[lrA * 4 + 3] = 1.0f / (1e-8f + 0.2f * dmA);
    sfeat[lrA * 4 + 4] = pB.x;
    sfeat[lrA * 4 + 5] = pB.y;
    sfeat[lrA * 4 + 6] = pB.z;
    sfeat[lrA * 4 + 7] = 1.0f / (1e-8f + 0.2f * dmB);
  }
  __syncthreads();
  {
    int c = tid & 63, rg = tid >> 6;
    float w0 = wT[c], w1 = wT[64 + c], w2v = wT[128 + c], w3v = wT[192 + c];
    float bb = lb1[c];
    int growbase = b * NPTS + blockIdx.x * 64;
    float s = 0.f, q = 0.f;
#pragma unroll
    for (int i = 0; i < 16; i++) {
      int lr = rg * 16 + i;
      float4 f = *(const float4*)(sfeat + lr * 4);
      float acc = bb + f.x * w0 + f.y * w1 + f.z * w2v + f.w * w3v;
      s += acc;
      q += acc * acc;
      z1bf[(size_t)(growbase + lr) * 64 + c] = f2bf(acc);
    }
    ls[tid] = s;
    lq[tid] = q;
  }
  __syncthreads();
  if (tid < 64) {
    float ss = 0.f, qq = 0.f;
#pragma unroll
    for (int i = 0; i < 4; i++) { ss += ls[i * 64 + tid]; qq += lq[i * 64 + tid]; }
    size_t bid = (size_t)b * 32 + blockIdx.x;
    part[(bid * 64 + tid) * 2 + 0] = ss;
    part[(bid * 64 + tid) * 2 + 1] = qq;
  }
}

// ---------------- generic BN finalize from P partials ----------------
template <int C, int P>
__global__ __launch_bounds__(256) void bnfinP_kernel(const float* __restrict__ part,
                                                     const float* __restrict__ g,
                                                     const float* __restrict__ be,
                                                     float* __restrict__ scale,
                                                     float* __restrict__ shift) {
  int c = blockIdx.x, tid = threadIdx.x;
  float s = 0.f, q = 0.f;
  for (int i = tid; i < P; i += 256) {
    s += part[((size_t)i * C + c) * 2 + 0];
    q += part[((size_t)i * C + c) * 2 + 1];
  }
  __shared__ float ls[256], lq[256];
  ls[tid] = s; lq[tid] = q;
  __syncthreads();
  for (int off = 128; off > 0; off >>= 1) {
    if (tid < off) { ls[tid] += ls[tid + off]; lq[tid] += lq[tid + off]; }
    __syncthreads();
  }
  if (tid == 0) {
    float m = ls[0] * (1.0f / 65536.0f);
    float v = lq[0] * (1.0f / 65536.0f) - m * m;
    float a = g[c] / sqrtf(v + EPS_BN);
    scale[c] = a;
    shift[c] = be[c] - m * a;
  }
}

// ---------------- layer2 MFMA: relu(bn1(z1bf)) @ W2^T + b2 -> z2bf + BN2 stats ----------------
__global__ __launch_bounds__(256) void gemm2_mfma_kernel(const unsigned short* __restrict__ z1bf,
                                                         const float* __restrict__ s1,
                                                         const float* __restrict__ h1,
                                                         const unsigned short* __restrict__ w2bf,
                                                         const float* __restrict__ bias2,
                                                         unsigned short* __restrict__ z2bf,
                                                         float* __restrict__ part2) {
  __shared__ char lds[33280];  // A @0 (16KB), B @16384 (16KB), s1h1 @32768
  float* ls1 = (float*)(lds + 32768);
  float* lh1 = ls1 + 64;
  int tid = threadIdx.x;
  int bid = blockIdx.x;
  int rblk = (bid & 7) * 64 + (bid >> 3);   // same mapping as gemm3
  int row0 = rblk * 128;
  if (tid < 64) { ls1[tid] = s1[tid]; lh1[tid] = h1[tid]; }

  s16x8 araw[4], braw[4];
#pragma unroll
  for (int i = 0; i < 4; i++) {
    int L = tid + 256 * i;
    araw[i] = *(const s16x8*)(z1bf + (size_t)row0 * 64 + (size_t)L * 8);
    braw[i] = *(const s16x8*)(w2bf + (size_t)L * 8);
  }
  __syncthreads();

#pragma unroll
  for (int i = 0; i < 4; i++) {
    int L = tid + 256 * i;
    int row = L >> 3, grp = L & 7, k0 = grp * 8;
    float4 sA = *(const float4*)(ls1 + k0);
    float4 sB = *(const float4*)(ls1 + k0 + 4);
    float4 hA = *(const float4*)(lh1 + k0);
    float4 hB = *(const float4*)(lh1 + k0 + 4);
    float v0 = fmaxf(bf2f((unsigned short)araw[i][0]) * sA.x + hA.x, 0.f);
    float v1 = fmaxf(bf2f((unsigned short)araw[i][1]) * sA.y + hA.y, 0.f);
    float v2 = fmaxf(bf2f((unsigned short)araw[i][2]) * sA.z + hA.z, 0.f);
    float v3 = fmaxf(bf2f((unsigned short)araw[i][3]) * sA.w + hA.w, 0.f);
    float v4 = fmaxf(bf2f((unsigned short)araw[i][4]) * sB.x + hB.x, 0.f);
    float v5 = fmaxf(bf2f((unsigned short)araw[i][5]) * sB.y + hB.y, 0.f);
    float v6 = fmaxf(bf2f((unsigned short)araw[i][6]) * sB.z + hB.z, 0.f);
    float v7 = fmaxf(bf2f((unsigned short)araw[i][7]) * sB.w + hB.w, 0.f);
    u32x4 pa = {pk2bf(v0, v1), pk2bf(v2, v3), pk2bf(v4, v5), pk2bf(v6, v7)};
    *(u32x4*)(lds + row * 128 + ((grp ^ (row & 7)) << 4)) = pa;
    *(s16x8*)(lds + 16384 + row * 128 + ((grp ^ (row & 7)) << 4)) = braw[i];
  }
  __syncthreads();

  int w = tid >> 6, lane = tid & 63;
  int wm = w >> 1, wn = w & 1;
  int lrow = lane & 15, lg = lane >> 4;
  int sw = (lrow & 7) << 4;
  f32x4 acc[4][4] = {};
#pragma unroll
  for (int kstep = 0; kstep < 2; kstep++) {
    s16x8 a[4], bfr[4];
#pragma unroll
    for (int m = 0; m < 4; m++) {
      int row = wm * 64 + m * 16 + lrow;
      int byte = row * 128 + ((kstep * 64 + lg * 16) ^ sw);
      a[m] = *(const s16x8*)(lds + byte);
    }
#pragma unroll
    for (int n = 0; n < 4; n++) {
      int col = wn * 64 + n * 16 + lrow;
      int byte = 16384 + col * 128 + ((kstep * 64 + lg * 16) ^ sw);
      bfr[n] = *(const s16x8*)(lds + byte);
    }
#pragma unroll
    for (int m = 0; m < 4; m++)
#pragma unroll
      for (int n = 0; n < 4; n++)
        acc[m][n] = __builtin_amdgcn_mfma_f32_16x16x32_bf16(a[m], bfr[n], acc[m][n], 0, 0, 0);
  }
  __syncthreads();

  float* sS = (float*)lds;
  float* sQ = sS + 256;
#pragma unroll
  for (int n = 0; n < 4; n++) {
    int col = wn * 64 + n * 16 + lrow;
    float bb = bias2[col];
    float s = 0.f, q = 0.f;
#pragma unroll
    for (int m = 0; m < 4; m++) {
#pragma unroll
      for (int r = 0; r < 4; r++) {
        float v = acc[m][n][r] + bb;
        s += v;
        q += v * v;
        int row = row0 + wm * 64 + m * 16 + lg * 4 + r;
        z2bf[(size_t)row * 128 + col] = f2bf(v);
      }
    }
    s += __shfl_xor(s, 16); s += __shfl_xor(s, 32);
    q += __shfl_xor(q, 16); q += __shfl_xor(q, 32);
    if (lane < 16) {
      int cidx = wn * 64 + n * 16 + lane;
      sS[wm * 128 + cidx] = s;
      sQ[wm * 128 + cidx] = q;
    }
  }
  __syncthreads();
  if (tid < 128) {
    part2[((size_t)rblk * 128 + tid) * 2 + 0] = sS[tid] + sS[128 + tid];
    part2[((size_t)rblk * 128 + tid) * 2 + 1] = sQ[tid] + sQ[128 + tid];
  }
}

// ---------------- layer3 MFMA: one block per 128-row panel, loop over 8 col-blocks ----------------
__global__ __launch_bounds__(256) void gemm3_mfma_kernel(const unsigned short* __restrict__ z2bf,
                                                         const float* __restrict__ s2,
                                                         const float* __restrict__ h2,
                                                         const unsigned short* __restrict__ wbf,
                                                         const float* __restrict__ bias3,
                                                         float* __restrict__ pS,
                                                         float* __restrict__ pQ,
                                                         float* __restrict__ pMx,
                                                         float* __restrict__ pMn) {
  __shared__ char lds[70656];  // A[0,32768) B[32768,65536) scratch[65536,69632) s2h2[69632,70656)
  float* ls2 = (float*)(lds + 69632);
  float* lh2 = ls2 + 128;
  int tid = threadIdx.x;
  int w = tid >> 6, lane = tid & 63;
  int bid = blockIdx.x;                 // 512 blocks, XCD-chunked
  int rblk = (bid & 7) * 64 + (bid >> 3);
  int row0 = rblk * 128;

  if (tid < 128) { ls2[tid] = s2[tid]; lh2[tid] = h2[tid]; }
  s16x8 araw[8];
#pragma unroll
  for (int i = 0; i < 8; i++) {
    int L = tid + 256 * i;
    int row = L >> 4, gc = L & 15;
    araw[i] = *(const s16x8*)(z2bf + (size_t)(row0 + row) * 128 + gc * 8);
  }
  __syncthreads();
#pragma unroll
  for (int i = 0; i < 8; i++) {
    int L = tid + 256 * i;
    int row = L >> 4, gc = L & 15, k0 = gc * 8;
    float4 sA = *(const float4*)(ls2 + k0);
    float4 sB = *(const float4*)(ls2 + k0 + 4);
    float4 hA = *(const float4*)(lh2 + k0);
    float4 hB = *(const float4*)(lh2 + k0 + 4);
    float v0 = fmaxf(bf2f((unsigned short)araw[i][0]) * sA.x + hA.x, 0.f);
    float v1 = fmaxf(bf2f((unsigned short)araw[i][1]) * sA.y + hA.y, 0.f);
    float v2 = fmaxf(bf2f((unsigned short)araw[i][2]) * sA.z + hA.z, 0.f);
    float v3 = fmaxf(bf2f((unsigned short)araw[i][3]) * sA.w + hA.w, 0.f);
    float v4 = fmaxf(bf2f((unsigned short)araw[i][4]) * sB.x + hB.x, 0.f);
    float v5 = fmaxf(bf2f((unsigned short)araw[i][5]) * sB.y + hB.y, 0.f);
    float v6 = fmaxf(bf2f((unsigned short)araw[i][6]) * sB.z + hB.z, 0.f);
    float v7 = fmaxf(bf2f((unsigned short)araw[i][7]) * sB.w + hB.w, 0.f);
    u32x4 pa = {pk2bf(v0, v1), pk2bf(v2, v3), pk2bf(v4, v5), pk2bf(v6, v7)};
    *(u32x4*)(lds + row * 256 + ((gc ^ (row & 7)) << 4)) = pa;
  }

  int wm = w >> 1, wn = w & 1;
  int lrow = lane & 15, lg = lane >> 4;
  int sw = (lrow & 7) << 4;
  float* sS = (float*)(lds + 65536);   // [2][128]
  float* sQ = sS + 256;
  float* sMx = sQ + 256;
  float* sMn = sMx + 256;

  for (int cblk = 0; cblk < 8; cblk++) {
    int col0 = cblk * 128;
#pragma unroll
    for (int i = 0; i < 8; i++) {
      int ldsoff = w * 8192 + i * 1024;
      int lin = ldsoff + lane * 16;
      int row = lin >> 8;
      int gc = (lin >> 4) & 15;
      int gcl = gc ^ (row & 7);
      gload_lds16(wbf + (size_t)(col0 + row) * 128 + gcl * 8, &lds[32768 + ldsoff]);
    }
    __syncthreads();

    f32x4 acc[4][4] = {};
#pragma unroll
    for (int kstep = 0; kstep < 4; kstep++) {
      s16x8 a[4], b[4];
#pragma unroll
      for (int m = 0; m < 4; m++) {
        int row = wm * 64 + m * 16 + lrow;
        int byte = row * 256 + ((kstep * 64 + lg * 16) ^ sw);
        a[m] = *(const s16x8*)(lds + byte);
      }
#pragma unroll
      for (int n = 0; n < 4; n++) {
        int col = wn * 64 + n * 16 + lrow;
        int byte = 32768 + col * 256 + ((kstep * 64 + lg * 16) ^ sw);
        b[n] = *(const s16x8*)(lds + byte);
      }
#pragma unroll
      for (int m = 0; m < 4; m++)
#pragma unroll
        for (int n = 0; n < 4; n++)
          acc[m][n] = __builtin_amdgcn_mfma_f32_16x16x32_bf16(a[m], b[n], acc[m][n], 0, 0, 0);
    }

#pragma unroll
    for (int n = 0; n < 4; n++) {
      float v[16];
      float s = 0.f, q = 0.f;
#pragma unroll
      for (int m = 0; m < 4; m++)
#pragma unroll
        for (int r = 0; r < 4; r++) {
          float t = acc[m][n][r];
          v[m * 4 + r] = t;
          s += t;
          q = fmaf(t, t, q);
        }
      float mx = fmaxf(fmaxf(fmaxf(fmaxf(v[0], v[1]), v[2]),
                             fmaxf(fmaxf(v[3], v[4]), v[5])),
                       fmaxf(fmaxf(fmaxf(v[6], v[7]), v[8]),
                             fmaxf(fmaxf(v[9], v[10]), v[11])));
      mx = fmaxf(mx, fmaxf(fmaxf(v[12], v[13]), fmaxf(v[14], v[15])));
      float mn = fminf(fminf(fminf(fminf(v[0], v[1]), v[2]),
                             fminf(fminf(v[3], v[4]), v[5])),
                       fminf(fminf(fminf(v[6], v[7]), v[8]),
                             fminf(fminf(v[9], v[10]), v[11])));
      mn = fminf(mn, fminf(fminf(v[12], v[13]), fminf(v[14], v[15])));
      s += __shfl_xor(s, 16); s += __shfl_xor(s, 32);
      q += __shfl_xor(q, 16); q += __shfl_xor(q, 32);
      mx = fmaxf(mx, __shfl_xor(mx, 16)); mx = fmaxf(mx, __shfl_xor(mx, 32));
      mn = fminf(mn, __shfl_xor(mn, 16)); mn = fminf(mn, __shfl_xor(mn, 32));
      if (lane < 16) {
        int cidx = wn * 64 + n * 16 + lane;
        sS[wm * 128 + cidx] = s;
        sQ[wm * 128 + cidx] = q;
        sMx[wm * 128 + cidx] = mx;
        sMn[wm * 128 + cidx] = mn;
      }
    }
    __syncthreads();
    if (tid < 128) {
      float bcol = bias3[col0 + tid];
      float S = sS[tid] + sS[128 + tid];
      float Q = sQ[tid] + sQ[128 + tid];
      size_t o = (size_t)rblk * 1024 + col0 + tid;
      pS[o] = S + 128.f * bcol;
      pQ[o] = Q + 2.f * bcol * S + 128.f * bcol * bcol;
      pMx[o] = fmaxf(sMx[tid], sMx[128 + tid]) + bcol;
      pMn[o] = fminf(sMn[tid], sMn[128 + tid]) + bcol;
    }
    __syncthreads();
  }
}

// ---------------- bn3 finalize + masked max-pool ----------------
__global__ __launch_bounds__(256) void bn3fin_pool_kernel(const float* __restrict__ pS,
                                                          const float* __restrict__ pQ,
                                                          const float* __restrict__ pMx,
                                                          const float* __restrict__ pMn,
                                                          const float* __restrict__ g,
                                                          const float* __restrict__ be,
                                                          float* __restrict__ pooled) {
  int tid = threadIdx.x;
  int chl = tid & 15, grp = tid >> 4;
  int c = blockIdx.x * 16 + chl;
  float s = 0.f, q = 0.f;
  for (int i = grp; i < 512; i += 16) {
    s += pS[(size_t)i * 1024 + c];
    q += pQ[(size_t)i * 1024 + c];
  }
  __shared__ float ls[256], lq[256], sa[16], sc[16];
  ls[chl * 16 + grp] = s;
  lq[chl * 16 + grp] = q;
  __syncthreads();
  if (tid < 16) {
    float ss = 0.f, qq = 0.f;
#pragma unroll
    for (int i = 0; i < 16; i++) { ss += ls[tid * 16 + i]; qq += lq[tid * 16 + i]; }
    float m = ss * (1.0f / 65536.0f);
    float v = qq * (1.0f / 65536.0f) - m * m;
    float a = g[blockIdx.x * 16 + tid] / sqrtf(v + EPS_BN);
    sa[tid] = a;
    sc[tid] = be[blockIdx.x * 16 + tid] - m * a;
  }
  __syncthreads();
  for (int idx = tid; idx < 512; idx += 256) {
    int b = idx >> 4, l = idx & 15;
    int cc = blockIdx.x * 16 + l;
    float mx = -3.4e38f, mn = 3.4e38f;
    for (int i = 0; i < 16; i++) {
      mx = fmaxf(mx, pMx[(size_t)(b * 16 + i) * 1024 + cc]);
      mn = fminf(mn, pMn[(size_t)(b * 16 + i) * 1024 + cc]);
    }
    float a = sa[l];
    float v = (a > 0.f) ? (a * mx + sc[l]) : (a * mn + sc[l]);
    pooled[(size_t)b * 1024 + cc] = fmaxf(v, 0.f);
  }
}

// ---------------- fc1: wave-per-output ----------------
__global__ __launch_bounds__(256) void fc1_kernel(const float* __restrict__ pooled,
                                                  const float* __restrict__ w,
                                                  const float* __restrict__ bias,
                                                  float* __restrict__ zf1) {
  int gw = blockIdx.x * 4 + (threadIdx.x >> 6);
  int lane = threadIdx.x & 63;
  int b = gw >> 9, o = gw & 511;
  const float4* pr = (const float4*)(pooled + (size_t)b * 1024);
  const float4* wr = (const float4*)(w + (size_t)o * 1024);
  float acc = 0.f;
#pragma unroll
  for (int i = 0; i < 4; i++) {
    int k = lane + i * 64;
    float4 p = pr[k], q = wr[k];
    acc += p.x * q.x + p.y * q.y + p.z * q.z + p.w * q.w;
  }
  acc = wave_reduce_add(acc);
  if (lane == 0) zf1[gw] = acc + bias[o];
}

__global__ __launch_bounds__(256) void statsF_kernel(const float* __restrict__ z,
                                                     const float* __restrict__ g,
                                                     const float* __restrict__ be, int C,
                                                     float* __restrict__ scale,
                                                     float* __restrict__ shift) {
  int c = blockIdx.x * 256 + threadIdx.x;
  if (c >= C) return;
  float s = 0.f, q = 0.f;
  for (int b = 0; b < 32; b++) {
    float v = z[(size_t)b * C + c];
    s += v;
    q += v * v;
  }
  float m = s * (1.0f / 32.0f);
  float v = q * (1.0f / 32.0f) - m * m;
  float a = g[c] / sqrtf(v + EPS_BN);
  scale[c] = a;
  shift[c] = be[c] - m * a;
}

// ---------------- fc2: wave-per-output ----------------
__global__ __launch_bounds__(256) void fc2_kernel(const float* __restrict__ zf1,
                                                  const float* __restrict__ sf1,
                                                  const float* __restrict__ hf1,
                                                  const float* __restrict__ w,
                                                  const float* __restrict__ bias,
                                                  float* __restrict__ zf2) {
  int gw = blockIdx.x * 4 + (threadIdx.x >> 6);
  int lane = threadIdx.x & 63;
  int b = gw >> 8, o = gw & 255;
  const float4* zr = (const float4*)(zf1 + (size_t)b * 512);
  const float4* sr = (const float4*)sf1;
  const float4* hr = (const float4*)hf1;
  const float4* wr = (const float4*)(w + (size_t)o * 512);
  float acc = 0.f;
#pragma unroll
  for (int i = 0; i < 2; i++) {
    int k = lane + i * 64;
    float4 z = zr[k], s = sr[k], h = hr[k], q = wr[k];
    float v0 = fmaxf(z.x * s.x + h.x, 0.f);
    float v1 = fmaxf(z.y * s.y + h.y, 0.f);
    float v2 = fmaxf(z.z * s.z + h.z, 0.f);
    float v3 = fmaxf(z.w * s.w + h.w, 0.f);
    acc += v0 * q.x + v1 * q.y + v2 * q.z + v3 * q.w;
  }
  acc = wave_reduce_add(acc);
  if (lane == 0) zf2[gw] = acc + bias[o];
}

// ---------------- head: per-block BN-f2 stats + 4 waves x 10 dots + log_softmax ----------------
__global__ __launch_bounds__(256) void head_kernel(const float* __restrict__ zf2,
                                                   const float* __restrict__ gf2,
                                                   const float* __restrict__ bef2,
                                                   const float* __restrict__ w,
                                                   const float* __restrict__ bias,
                                                   float* __restrict__ out) {
  int b = blockIdx.x, tid = threadIdx.x;
  int wv = tid >> 6, lane = tid & 63;
  __shared__ float ssf[256], shf[256], lg[40], red[2];
  {
    float s = 0.f, q = 0.f;
    for (int bb = 0; bb < 32; bb++) {
      float v = zf2[(size_t)bb * 256 + tid];
      s += v;
      q += v * v;
    }
    float m = s * (1.0f / 32.0f);
    float var = q * (1.0f / 32.0f) - m * m;
    float a = gf2[tid] / sqrtf(var + EPS_BN);
    ssf[tid] = a;
    shf[tid] = bef2[tid] - m * a;
  }
  __syncthreads();
  float4 z = ((const float4*)(zf2 + (size_t)b * 256))[lane];
  float4 s = ((const float4*)ssf)[lane];
  float4 h = ((const float4*)shf)[lane];
  float v0 = fmaxf(z.x * s.x + h.x, 0.f);
  float v1 = fmaxf(z.y * s.y + h.y, 0.f);
  float v2 = fmaxf(z.z * s.z + h.z, 0.f);
  float v3 = fmaxf(z.w * s.w + h.w, 0.f);
  for (int r = 0; r < 10; r++) {
    int o = wv * 10 + r;
    float4 q = ((const float4*)(w + (size_t)o * 256))[lane];
    float a = v0 * q.x + v1 * q.y + v2 * q.z + v3 * q.w;
    a = wave_reduce_add(a);
    if (lane == 0) lg[o] = a + bias[o];
  }
  __syncthreads();
  if (tid == 0) {
    float mx = -3.4e38f;
    for (int i = 0; i < 40; i++) mx = fmaxf(mx, lg[i]);
    float sum = 0.f;
    for (int i = 0; i < 40; i++) sum += expf(lg[i] - mx);
    red[0] = mx;
    red[1] = logf(sum);
  }
  __syncthreads();
  if (tid < 40) out[(size_t)b * 40 + tid] = lg[tid] - red[0] - red[1];
}

extern "C" void kernel_launch(void* const* d_in, const int* in_sizes, int n_in,
                              void* d_out, int out_size, void* d_ws, size_t ws_size,
                              hipStream_t stream) {
  const float* x    = (const float*)d_in[0];
  const float* c1w  = (const float*)d_in[1];
  const float* c1b  = (const float*)d_in[2];
  const float* g1   = (const float*)d_in[3];
  const float* be1  = (const float*)d_in[4];
  const float* c2w  = (const float*)d_in[5];
  const float* c2b  = (const float*)d_in[6];
  const float* g2   = (const float*)d_in[7];
  const float* be2  = (const float*)d_in[8];
  const float* c3w  = (const float*)d_in[9];
  const float* c3b  = (const float*)d_in[10];
  const float* g3   = (const float*)d_in[11];
  const float* be3  = (const float*)d_in[12];
  const float* f1w  = (const float*)d_in[13];
  const float* f1b  = (const float*)d_in[14];
  const float* gf1  = (const float*)d_in[15];
  const float* bef1 = (const float*)d_in[16];
  const float* f2w  = (const float*)d_in[17];
  const float* f2b  = (const float*)d_in[18];
  const float* gf2  = (const float*)d_in[19];
  const float* bef2 = (const float*)d_in[20];
  const float* ow   = (const float*)d_in[21];
  const float* ob   = (const float*)d_in[22];
  float* out = (float*)d_out;

  float* W = (float*)d_ws;
  float* pS     = W;                   // 524288
  float* pQ     = pS + 524288;
  float* pMx    = pQ + 524288;
  float* pMn    = pMx + 524288;
  float* part   = pMn + 524288;        // 131072 (BN1 partials 1024x64x2)
  float* part2  = part + 262144;       // 131072 (BN2 partials 512x128x2)
  float* pooled = part2 + 131072;      // 32768
  float* zf1    = pooled + 32768;      // 16384
  float* zf2    = zf1 + 16384;         // 8192
  float* s1     = zf2 + 8192;          // 64
  float* h1     = s1 + 64;
  float* s2     = h1 + 64;             // 128
  float* h2     = s2 + 128;
  float* sf1    = h2 + 128;            // 512
  float* hf1    = sf1 + 512;
  unsigned short* wbf  = (unsigned short*)(hf1 + 512);   // 131072 shorts (w3 bf16)
  unsigned short* w2bf = wbf + 131072;                   // 8192 shorts (w2 bf16)
  unsigned short* z1bf = w2bf + 8192;                    // 65536*64
  unsigned short* z2bf = z1bf + (size_t)BP * 64;         // 65536*128

  curv1_kernel<<<dim3(32, 33), 256, 0, stream>>>(x, c1w, c1b, c3w, c2w, wbf, w2bf, z1bf, part);
  bnfinP_kernel<64, 1024><<<64, 256, 0, stream>>>(part, g1, be1, s1, h1);
  gemm2_mfma_kernel<<<512, 256, 0, stream>>>(z1bf, s1, h1, w2bf, c2b, z2bf, part2);
  bnfinP_kernel<128, 512><<<128, 256, 0, stream>>>(part2, g2, be2, s2, h2);
  gemm3_mfma_kernel<<<512, 256, 0, stream>>>(z2bf, s2, h2, wbf, c3b, pS, pQ, pMx, pMn);
  bn3fin_pool_kernel<<<64, 256, 0, stream>>>(pS, pQ, pMx, pMn, g3, be3, pooled);
  fc1_kernel<<<4096, 256, 0, stream>>>(pooled, f1w, f1b, zf1);
  statsF_kernel<<<2, 256, 0, stream>>>(zf1, gf1, bef1, 512, sf1, hf1);
  fc2_kernel<<<2048, 256, 0, stream>>>(zf1, sf1, hf1, f2w, f2b, zf2);
  head_kernel<<<32, 256, 0, stream>>>(zf2, gf2, bef2, ow, ob, out);
}